// Round 1
// baseline (1372.254 us; speedup 1.0000x reference)
//
#include <hip/hip_runtime.h>
#include <hip/hip_bf16.h>

#define NN 2048
#define QQ 9
#define DD 256
#define LL 4
#define BB 32
#define EE 32768
#define EPSV 1e-5f

// ---------- h0 = batch_feature with rows [0,Q) replaced by emotion_emb ----------
__global__ void k_init(const float4* __restrict__ bf, const float4* __restrict__ emo,
                       float4* __restrict__ h)
{
    int total = BB * NN * (DD / 4);
    for (int idx = blockIdx.x * blockDim.x + threadIdx.x; idx < total;
         idx += gridDim.x * blockDim.x) {
        int d4 = idx & 63;
        int n  = (idx >> 6) & (NN - 1);
        h[idx] = (n < QQ) ? emo[n * 64 + d4] : bf[idx];
    }
}

// ---------- CSR build ----------
__global__ void k_count(const int* __restrict__ src, int* __restrict__ cnt)
{
    int e = blockIdx.x * blockDim.x + threadIdx.x;
    if (e < EE) atomicAdd(&cnt[src[e]], 1);
}

__global__ __launch_bounds__(256) void k_scan(const int* __restrict__ cnt,
                                              int* __restrict__ row_ptr,
                                              int* __restrict__ cursor)
{
    __shared__ int part[256];
    int t = threadIdx.x;
    int local[8];
    int s = 0;
    #pragma unroll
    for (int i = 0; i < 8; ++i) { local[i] = cnt[t * 8 + i]; s += local[i]; }
    part[t] = s;
    __syncthreads();
    for (int off = 1; off < 256; off <<= 1) {
        int v = (t >= off) ? part[t - off] : 0;
        __syncthreads();
        part[t] += v;
        __syncthreads();
    }
    int run = part[t] - s;  // exclusive prefix of this thread's chunk
    #pragma unroll
    for (int i = 0; i < 8; ++i) {
        int idx = t * 8 + i;
        row_ptr[idx] = run;
        cursor[idx]  = run;
        run += local[i];
    }
    if (t == 255) row_ptr[NN] = run;
}

__global__ void k_fill(const int* __restrict__ src, const int* __restrict__ dst,
                       int* __restrict__ cursor, int* __restrict__ col)
{
    int e = blockIdx.x * blockDim.x + threadIdx.x;
    if (e < EE) {
        int p = atomicAdd(&cursor[src[e]], 1);
        col[p] = dst[e];
    }
}

// ---------- pooled[b,n] = h[b,n] + sum_{e: src==n} h[b, dst[e]] ----------
__global__ __launch_bounds__(64) void k_spmm(const float4* __restrict__ h,
                                             const int* __restrict__ row_ptr,
                                             const int* __restrict__ col,
                                             float4* __restrict__ pooled)
{
    int bid = blockIdx.x;           // b*NN + n
    int n = bid & (NN - 1);
    int b = bid >> 11;
    int t = threadIdx.x;            // 64 lanes, float4 each -> 256 floats
    const float4* hb = h + (size_t)b * NN * 64;
    float4 acc = hb[n * 64 + t];
    int beg = row_ptr[n], end = row_ptr[n + 1];
    for (int j = beg; j < end; ++j) {
        int c = col[j];
        float4 v = hb[c * 64 + t];
        acc.x += v.x; acc.y += v.y; acc.z += v.z; acc.w += v.w;
    }
    pooled[(size_t)bid * 64 + t] = acc;
}

// ---------- O = relu( bn( A @ W + bias ) ), A: (M=65536, 256), W: (256, 256) ----------
__global__ __launch_bounds__(256) void k_gemm_bn_relu(
    const float* __restrict__ A, const float* __restrict__ W,
    const float* __restrict__ bias, const float* __restrict__ gg,
    const float* __restrict__ bb, const float* __restrict__ mm,
    const float* __restrict__ vv, float* __restrict__ O)
{
    __shared__ float As[16][68];
    __shared__ float Bs[16][68];
    int tid = threadIdx.x;
    int bm0 = (int)(blockIdx.x >> 2) * 64;
    int bn0 = (int)(blockIdx.x & 3) * 64;
    int ty = tid >> 4, tx = tid & 15;
    float acc[4][4];
    #pragma unroll
    for (int i = 0; i < 4; ++i)
        #pragma unroll
        for (int j = 0; j < 4; ++j) acc[i][j] = 0.f;

    int arow = tid >> 2, akq = tid & 3;   // A tile loader: 64 rows x 16 k
    int brow = tid >> 4, bjq = tid & 15;  // W tile loader: 16 k x 64 j
    const float* Aload = A + (size_t)(bm0 + arow) * DD + akq * 4;
    const float* Wload = W + (size_t)brow * DD + bn0 + bjq * 4;

    for (int k0 = 0; k0 < DD; k0 += 16) {
        float4 av = *(const float4*)(Aload + k0);
        float4 wv = *(const float4*)(Wload + (size_t)k0 * DD);
        __syncthreads();
        As[akq * 4 + 0][arow] = av.x;
        As[akq * 4 + 1][arow] = av.y;
        As[akq * 4 + 2][arow] = av.z;
        As[akq * 4 + 3][arow] = av.w;
        *(float4*)&Bs[brow][bjq * 4] = wv;
        __syncthreads();
        #pragma unroll
        for (int kk = 0; kk < 16; ++kk) {
            float4 a  = *(const float4*)&As[kk][ty * 4];
            float4 bq = *(const float4*)&Bs[kk][tx * 4];
            const float* ap = (const float*)&a;
            const float* bp = (const float*)&bq;
            #pragma unroll
            for (int i = 0; i < 4; ++i)
                #pragma unroll
                for (int j = 0; j < 4; ++j)
                    acc[i][j] = fmaf(ap[i], bp[j], acc[i][j]);
        }
    }
    // epilogue: y = relu(acc*s + (bias - m)*s + b)
    float sc[4], sh[4];
    #pragma unroll
    for (int j = 0; j < 4; ++j) {
        int jj = bn0 + tx * 4 + j;
        float s = gg[jj] * rsqrtf(vv[jj] + EPSV);
        sc[j] = s;
        sh[j] = (bias[jj] - mm[jj]) * s + bb[jj];
    }
    #pragma unroll
    for (int i = 0; i < 4; ++i) {
        int m = bm0 + ty * 4 + i;
        float4 o;
        float* op = (float*)&o;
        #pragma unroll
        for (int j = 0; j < 4; ++j) {
            float y = acc[i][j] * sc[j] + sh[j];
            op[j] = y > 0.f ? y : 0.f;
        }
        *(float4*)&O[(size_t)m * DD + bn0 + tx * 4] = o;
    }
}

// ---------- score[b,q] += h[b,q,:].pred_w[l] + pred_b[l] ----------
__global__ __launch_bounds__(64) void k_score(const float4* __restrict__ h,
                                              const float4* __restrict__ pw,
                                              const float* __restrict__ pb, int l,
                                              float* __restrict__ out)
{
    int bid = blockIdx.x;  // B*Q
    int b = bid / QQ, q = bid % QQ;
    int t = threadIdx.x;
    float4 hv = h[((size_t)b * NN + q) * 64 + t];
    float4 wv = pw[l * 64 + t];
    float sum = hv.x * wv.x + hv.y * wv.y + hv.z * wv.z + hv.w * wv.w;
    #pragma unroll
    for (int off = 32; off > 0; off >>= 1)
        sum += __shfl_down(sum, off);
    if (t == 0) out[bid] += sum + pb[l];
}

__global__ void k_sigmoid(float* out)
{
    int i = threadIdx.x + blockIdx.x * blockDim.x;
    if (i < BB * QQ) out[i] = 1.f / (1.f + expf(-out[i]));
}

extern "C" void kernel_launch(void* const* d_in, const int* in_sizes, int n_in,
                              void* d_out, int out_size, void* d_ws, size_t ws_size,
                              hipStream_t stream)
{
    const float* batch = (const float*)d_in[0];
    const int*   edges = (const int*)d_in[1];
    const float* emo   = (const float*)d_in[2];
    const float* w1    = (const float*)d_in[3];
    const float* b1    = (const float*)d_in[4];
    const float* m_g   = (const float*)d_in[5];
    const float* m_b   = (const float*)d_in[6];
    const float* m_m   = (const float*)d_in[7];
    const float* m_v   = (const float*)d_in[8];
    const float* w2    = (const float*)d_in[9];
    const float* b2    = (const float*)d_in[10];
    const float* g_g   = (const float*)d_in[11];
    const float* g_b   = (const float*)d_in[12];
    const float* g_m   = (const float*)d_in[13];
    const float* g_v   = (const float*)d_in[14];
    const float* pw    = (const float*)d_in[15];
    const float* pb    = (const float*)d_in[16];
    float* out = (float*)d_out;

    float* buf0 = (float*)d_ws;
    float* buf1 = buf0 + (size_t)BB * NN * DD;
    int* cnt     = (int*)(buf1 + (size_t)BB * NN * DD);
    int* row_ptr = cnt + NN;
    int* cursor  = row_ptr + (NN + 1);
    int* col     = cursor + NN;

    const int* src = edges;
    const int* dst = edges + EE;

    hipMemsetAsync(cnt, 0, NN * sizeof(int), stream);
    hipMemsetAsync(d_out, 0, BB * QQ * sizeof(float), stream);
    k_init<<<4096, 256, 0, stream>>>((const float4*)batch, (const float4*)emo,
                                     (float4*)buf0);
    k_count<<<EE / 256, 256, 0, stream>>>(src, cnt);
    k_scan<<<1, 256, 0, stream>>>(cnt, row_ptr, cursor);
    k_fill<<<EE / 256, 256, 0, stream>>>(src, dst, cursor, col);
    k_score<<<BB * QQ, 64, 0, stream>>>((const float4*)buf0, (const float4*)pw,
                                        pb, 0, out);

    float* hcur = buf0;
    float* hnext = buf1;
    for (int l = 0; l < LL; ++l) {
        k_spmm<<<BB * NN, 64, 0, stream>>>((const float4*)hcur, row_ptr, col,
                                           (float4*)hnext);
        // t = relu(bn1(pooled @ w1 + b1)) : pooled in hnext -> hcur
        k_gemm_bn_relu<<<(BB * NN / 64) * 4, 256, 0, stream>>>(
            hnext, w1 + (size_t)l * DD * DD, b1 + l * DD, m_g + l * DD,
            m_b + l * DD, m_m + l * DD, m_v + l * DD, hcur);
        // h = relu(bn2(t @ w2 + b2)) : t in hcur -> hnext
        k_gemm_bn_relu<<<(BB * NN / 64) * 4, 256, 0, stream>>>(
            hcur, w2 + (size_t)l * DD * DD, b2 + l * DD, g_g + l * DD,
            g_b + l * DD, g_m + l * DD, g_v + l * DD, hnext);
        k_score<<<BB * QQ, 64, 0, stream>>>((const float4*)hnext,
                                            (const float4*)pw, pb, l + 1, out);
        float* tmp = hcur; hcur = hnext; hnext = tmp;
    }
    k_sigmoid<<<1, 288, 0, stream>>>(out);
}

// Round 2
// 809.503 us; speedup vs baseline: 1.6952x; 1.6952x over previous
//
#include <hip/hip_runtime.h>
#include <hip/hip_bf16.h>

#define NN 2048
#define QQ 9
#define DD 256
#define LL 4
#define BB 32
#define EE 32768
#define EPSV 1e-5f

typedef __attribute__((ext_vector_type(8))) short bf16x8;
typedef __attribute__((ext_vector_type(4))) float f32x4;

__device__ __forceinline__ ushort f2bf(float x)
{
    uint u = __float_as_uint(x);
    u += 0x7FFFu + ((u >> 16) & 1u);
    return (ushort)(u >> 16);
}
__device__ __forceinline__ float bf2f(ushort h)
{
    return __uint_as_float(((uint)h) << 16);
}

// ---------- h0 = batch_feature with rows [0,Q) replaced by emotion_emb ----------
__global__ void k_init(const float4* __restrict__ bf, const float4* __restrict__ emo,
                       float4* __restrict__ h)
{
    int total = BB * NN * (DD / 4);
    for (int idx = blockIdx.x * blockDim.x + threadIdx.x; idx < total;
         idx += gridDim.x * blockDim.x) {
        int d4 = idx & 63;
        int n  = (idx >> 6) & (NN - 1);
        h[idx] = (n < QQ) ? emo[n * 64 + d4] : bf[idx];
    }
}

// ---------- CSR build ----------
__global__ void k_count(const int* __restrict__ src, int* __restrict__ cnt)
{
    int e = blockIdx.x * blockDim.x + threadIdx.x;
    if (e < EE) atomicAdd(&cnt[src[e]], 1);
}

__global__ __launch_bounds__(256) void k_scan(const int* __restrict__ cnt,
                                              int* __restrict__ row_ptr,
                                              int* __restrict__ cursor)
{
    __shared__ int part[256];
    int t = threadIdx.x;
    int local[8];
    int s = 0;
    #pragma unroll
    for (int i = 0; i < 8; ++i) { local[i] = cnt[t * 8 + i]; s += local[i]; }
    part[t] = s;
    __syncthreads();
    for (int off = 1; off < 256; off <<= 1) {
        int v = (t >= off) ? part[t - off] : 0;
        __syncthreads();
        part[t] += v;
        __syncthreads();
    }
    int run = part[t] - s;
    #pragma unroll
    for (int i = 0; i < 8; ++i) {
        int idx = t * 8 + i;
        row_ptr[idx] = run;
        cursor[idx]  = run;
        run += local[i];
    }
    if (t == 255) row_ptr[NN] = run;
}

__global__ void k_fill(const int* __restrict__ src, const int* __restrict__ dst,
                       int* __restrict__ cursor, int* __restrict__ col)
{
    int e = blockIdx.x * blockDim.x + threadIdx.x;
    if (e < EE) {
        int p = atomicAdd(&cursor[src[e]], 1);
        col[p] = dst[e];
    }
}

// ---------- pooled[b,n] = h[b,n] + sum_{e: src==n} h[b, dst[e]] ----------
__global__ __launch_bounds__(64) void k_spmm(const float4* __restrict__ h,
                                             const int* __restrict__ row_ptr,
                                             const int* __restrict__ col,
                                             float4* __restrict__ pooled)
{
    int bid = blockIdx.x;           // b*NN + n
    int n = bid & (NN - 1);
    int b = bid >> 11;
    int t = threadIdx.x;
    const float4* hb = h + (size_t)b * NN * 64;
    float4 acc = hb[n * 64 + t];
    int beg = row_ptr[n], end = row_ptr[n + 1];
    for (int j = beg; j < end; ++j) {
        int c = col[j];
        float4 v = hb[c * 64 + t];
        acc.x += v.x; acc.y += v.y; acc.z += v.z; acc.w += v.w;
    }
    pooled[(size_t)bid * 64 + t] = acc;
}

// ---------- weight prep: Wt_hi/lo[mat][n][k] = split(W[mat][k][n]) ----------
__global__ __launch_bounds__(256) void k_wprep(const float* __restrict__ w1,
                                               const float* __restrict__ w2,
                                               ushort* __restrict__ wt_hi,
                                               ushort* __restrict__ wt_lo)
{
    __shared__ float tile[32][36];
    int bx = blockIdx.x;
    int mat = bx >> 6;
    int tt  = bx & 63;
    int tk = (tt >> 3) * 32;
    int tn = (tt & 7) * 32;
    const float* src = (mat < 4) ? (w1 + (size_t)mat * DD * DD)
                                 : (w2 + (size_t)(mat - 4) * DD * DD);
    int t = threadIdx.x;
    int r = t >> 3, c0 = (t & 7) * 4;
    float4 v = *(const float4*)(src + (size_t)(tk + r) * DD + tn + c0);
    tile[r][c0 + 0] = v.x; tile[r][c0 + 1] = v.y;
    tile[r][c0 + 2] = v.z; tile[r][c0 + 3] = v.w;
    __syncthreads();
    int nn = t >> 3, kq = (t & 7) * 4;
    ushort4 hh, ll;
    float x0 = tile[kq + 0][nn], x1 = tile[kq + 1][nn];
    float x2 = tile[kq + 2][nn], x3 = tile[kq + 3][nn];
    hh.x = f2bf(x0); hh.y = f2bf(x1); hh.z = f2bf(x2); hh.w = f2bf(x3);
    ll.x = f2bf(x0 - bf2f(hh.x)); ll.y = f2bf(x1 - bf2f(hh.y));
    ll.z = f2bf(x2 - bf2f(hh.z)); ll.w = f2bf(x3 - bf2f(hh.w));
    size_t off = (size_t)mat * DD * DD + (size_t)(tn + nn) * DD + tk + kq;
    *(ushort4*)(wt_hi + off) = hh;
    *(ushort4*)(wt_lo + off) = ll;
}

// ---------- MFMA split-bf16 GEMM: O = relu(bn(A @ W + bias)) ----------
// A: (65536, 256) fp32, W pre-transposed/split: Wt[n][k] bf16 hi/lo
__global__ __launch_bounds__(256) void k_gemm_mfma(
    const float* __restrict__ A, const ushort* __restrict__ wt_hi,
    const ushort* __restrict__ wt_lo,
    const float* __restrict__ bias, const float* __restrict__ gg,
    const float* __restrict__ bb, const float* __restrict__ mm,
    const float* __restrict__ vv, float* __restrict__ O)
{
    __shared__ ushort As_hi[128][40];
    __shared__ ushort As_lo[128][40];
    __shared__ ushort Ws_hi[128][40];
    __shared__ ushort Ws_lo[128][40];
    int tid = threadIdx.x;
    int bm0 = (int)(blockIdx.x >> 1) * 128;
    int bn0 = (int)(blockIdx.x & 1) * 128;
    int lane = tid & 63;
    int w = tid >> 6;
    int wm = w & 1, wn = w >> 1;
    int lr = lane & 15, kg = lane >> 4;

    f32x4 acc[4][4];
    #pragma unroll
    for (int m = 0; m < 4; ++m)
        #pragma unroll
        for (int n = 0; n < 4; ++n) acc[m][n] = (f32x4)0.f;

    for (int kc = 0; kc < 8; ++kc) {
        int k0 = kc * 32;
        __syncthreads();
        // stage A: 128 rows x 32 k, fp32 -> hi/lo bf16
        #pragma unroll
        for (int i = 0; i < 4; ++i) {
            int idx = tid + i * 256;
            int r = idx >> 3, k4 = (idx & 7) * 4;
            float4 v = *(const float4*)(A + (size_t)(bm0 + r) * DD + k0 + k4);
            ushort4 hh, ll;
            hh.x = f2bf(v.x); hh.y = f2bf(v.y); hh.z = f2bf(v.z); hh.w = f2bf(v.w);
            ll.x = f2bf(v.x - bf2f(hh.x)); ll.y = f2bf(v.y - bf2f(hh.y));
            ll.z = f2bf(v.z - bf2f(hh.z)); ll.w = f2bf(v.w - bf2f(hh.w));
            *(ushort4*)&As_hi[r][k4] = hh;
            *(ushort4*)&As_lo[r][k4] = ll;
        }
        // stage W: 128 cols x 32 k from pre-split transposed weights
        #pragma unroll
        for (int i = 0; i < 2; ++i) {
            int idx = tid + i * 256;
            int r = idx >> 2, kq = (idx & 3) * 8;
            size_t g = (size_t)(bn0 + r) * DD + k0 + kq;
            *(float4*)&Ws_hi[r][kq] = *(const float4*)(wt_hi + g);
            *(float4*)&Ws_lo[r][kq] = *(const float4*)(wt_lo + g);
        }
        __syncthreads();
        bf16x8 ah[4], al[4], bh[4], bl[4];
        #pragma unroll
        for (int m = 0; m < 4; ++m) {
            ah[m] = *(const bf16x8*)&As_hi[wm * 64 + m * 16 + lr][kg * 8];
            al[m] = *(const bf16x8*)&As_lo[wm * 64 + m * 16 + lr][kg * 8];
        }
        #pragma unroll
        for (int n = 0; n < 4; ++n) {
            bh[n] = *(const bf16x8*)&Ws_hi[wn * 64 + n * 16 + lr][kg * 8];
            bl[n] = *(const bf16x8*)&Ws_lo[wn * 64 + n * 16 + lr][kg * 8];
        }
        #pragma unroll
        for (int m = 0; m < 4; ++m)
            #pragma unroll
            for (int n = 0; n < 4; ++n) {
                acc[m][n] = __builtin_amdgcn_mfma_f32_16x16x32_bf16(ah[m], bh[n], acc[m][n], 0, 0, 0);
                acc[m][n] = __builtin_amdgcn_mfma_f32_16x16x32_bf16(ah[m], bl[n], acc[m][n], 0, 0, 0);
                acc[m][n] = __builtin_amdgcn_mfma_f32_16x16x32_bf16(al[m], bh[n], acc[m][n], 0, 0, 0);
            }
    }
    // epilogue: y = relu(acc*s + (bias - m)*s + b)
    int rg = lane >> 4;
    #pragma unroll
    for (int n = 0; n < 4; ++n) {
        int jj = bn0 + wn * 64 + n * 16 + lr;
        float s  = gg[jj] * rsqrtf(vv[jj] + EPSV);
        float sh = (bias[jj] - mm[jj]) * s + bb[jj];
        #pragma unroll
        for (int m = 0; m < 4; ++m) {
            int row = bm0 + wm * 64 + m * 16 + rg * 4;
            #pragma unroll
            for (int r = 0; r < 4; ++r) {
                float y = acc[m][n][r] * s + sh;
                O[(size_t)(row + r) * DD + jj] = y > 0.f ? y : 0.f;
            }
        }
    }
}

// ---------- fp32 fallback GEMM (used only if ws too small) ----------
__global__ __launch_bounds__(256) void k_gemm_bn_relu(
    const float* __restrict__ A, const float* __restrict__ W,
    const float* __restrict__ bias, const float* __restrict__ gg,
    const float* __restrict__ bb, const float* __restrict__ mm,
    const float* __restrict__ vv, float* __restrict__ O)
{
    __shared__ float As[16][68];
    __shared__ float Bs[16][68];
    int tid = threadIdx.x;
    int bm0 = (int)(blockIdx.x >> 2) * 64;
    int bn0 = (int)(blockIdx.x & 3) * 64;
    int ty = tid >> 4, tx = tid & 15;
    float acc[4][4];
    #pragma unroll
    for (int i = 0; i < 4; ++i)
        #pragma unroll
        for (int j = 0; j < 4; ++j) acc[i][j] = 0.f;
    int arow = tid >> 2, akq = tid & 3;
    int brow = tid >> 4, bjq = tid & 15;
    const float* Aload = A + (size_t)(bm0 + arow) * DD + akq * 4;
    const float* Wload = W + (size_t)brow * DD + bn0 + bjq * 4;
    for (int k0 = 0; k0 < DD; k0 += 16) {
        float4 av = *(const float4*)(Aload + k0);
        float4 wv = *(const float4*)(Wload + (size_t)k0 * DD);
        __syncthreads();
        As[akq * 4 + 0][arow] = av.x;
        As[akq * 4 + 1][arow] = av.y;
        As[akq * 4 + 2][arow] = av.z;
        As[akq * 4 + 3][arow] = av.w;
        *(float4*)&Bs[brow][bjq * 4] = wv;
        __syncthreads();
        #pragma unroll
        for (int kk = 0; kk < 16; ++kk) {
            float4 a  = *(const float4*)&As[kk][ty * 4];
            float4 bq = *(const float4*)&Bs[kk][tx * 4];
            const float* ap = (const float*)&a;
            const float* bp = (const float*)&bq;
            #pragma unroll
            for (int i = 0; i < 4; ++i)
                #pragma unroll
                for (int j = 0; j < 4; ++j)
                    acc[i][j] = fmaf(ap[i], bp[j], acc[i][j]);
        }
    }
    float sc[4], sh[4];
    #pragma unroll
    for (int j = 0; j < 4; ++j) {
        int jj = bn0 + tx * 4 + j;
        float s = gg[jj] * rsqrtf(vv[jj] + EPSV);
        sc[j] = s;
        sh[j] = (bias[jj] - mm[jj]) * s + bb[jj];
    }
    #pragma unroll
    for (int i = 0; i < 4; ++i) {
        int m = bm0 + ty * 4 + i;
        float4 o;
        float* op = (float*)&o;
        #pragma unroll
        for (int j = 0; j < 4; ++j) {
            float y = acc[i][j] * sc[j] + sh[j];
            op[j] = y > 0.f ? y : 0.f;
        }
        *(float4*)&O[(size_t)m * DD + bn0 + tx * 4] = o;
    }
}

// ---------- score[b,q] += h[b,q,:].pred_w[l] + pred_b[l] ----------
__global__ __launch_bounds__(64) void k_score(const float4* __restrict__ h,
                                              const float4* __restrict__ pw,
                                              const float* __restrict__ pb, int l,
                                              float* __restrict__ out)
{
    int bid = blockIdx.x;
    int b = bid / QQ, q = bid % QQ;
    int t = threadIdx.x;
    float4 hv = h[((size_t)b * NN + q) * 64 + t];
    float4 wv = pw[l * 64 + t];
    float sum = hv.x * wv.x + hv.y * wv.y + hv.z * wv.z + hv.w * wv.w;
    #pragma unroll
    for (int off = 32; off > 0; off >>= 1)
        sum += __shfl_down(sum, off);
    if (t == 0) out[bid] += sum + pb[l];
}

__global__ void k_sigmoid(float* out)
{
    int i = threadIdx.x + blockIdx.x * blockDim.x;
    if (i < BB * QQ) out[i] = 1.f / (1.f + expf(-out[i]));
}

extern "C" void kernel_launch(void* const* d_in, const int* in_sizes, int n_in,
                              void* d_out, int out_size, void* d_ws, size_t ws_size,
                              hipStream_t stream)
{
    const float* batch = (const float*)d_in[0];
    const int*   edges = (const int*)d_in[1];
    const float* emo   = (const float*)d_in[2];
    const float* w1    = (const float*)d_in[3];
    const float* b1    = (const float*)d_in[4];
    const float* m_g   = (const float*)d_in[5];
    const float* m_b   = (const float*)d_in[6];
    const float* m_m   = (const float*)d_in[7];
    const float* m_v   = (const float*)d_in[8];
    const float* w2    = (const float*)d_in[9];
    const float* b2    = (const float*)d_in[10];
    const float* g_g   = (const float*)d_in[11];
    const float* g_b   = (const float*)d_in[12];
    const float* g_m   = (const float*)d_in[13];
    const float* g_v   = (const float*)d_in[14];
    const float* pw    = (const float*)d_in[15];
    const float* pb    = (const float*)d_in[16];
    float* out = (float*)d_out;

    const size_t HSZ = (size_t)BB * NN * DD;           // 16M floats
    const size_t WT  = (size_t)8 * DD * DD;            // 512K ushorts per array

    float* buf0 = (float*)d_ws;
    float* buf1 = buf0 + HSZ;
    // MFMA path layout (needs ~130.2 MB)
    size_t need_mfma = 2 * HSZ * 4 + 2 * WT * 2 +
                       (size_t)(NN + NN + 1 + NN + EE) * 4;
    bool use_mfma = ws_size >= need_mfma;

    ushort* wt_hi = (ushort*)(buf1 + HSZ);
    ushort* wt_lo = wt_hi + WT;
    int* cnt     = use_mfma ? (int*)(wt_lo + WT) : (int*)(buf1 + HSZ);
    int* row_ptr = cnt + NN;
    int* cursor  = row_ptr + (NN + 1);
    int* col     = cursor + NN;

    const int* src = edges;
    const int* dst = edges + EE;

    hipMemsetAsync(cnt, 0, NN * sizeof(int), stream);
    hipMemsetAsync(d_out, 0, BB * QQ * sizeof(float), stream);
    k_init<<<4096, 256, 0, stream>>>((const float4*)batch, (const float4*)emo,
                                     (float4*)buf0);
    k_count<<<EE / 256, 256, 0, stream>>>(src, cnt);
    k_scan<<<1, 256, 0, stream>>>(cnt, row_ptr, cursor);
    k_fill<<<EE / 256, 256, 0, stream>>>(src, dst, cursor, col);
    if (use_mfma)
        k_wprep<<<512, 256, 0, stream>>>(w1, w2, wt_hi, wt_lo);
    k_score<<<BB * QQ, 64, 0, stream>>>((const float4*)buf0, (const float4*)pw,
                                        pb, 0, out);

    float* hcur = buf0;
    float* hnext = buf1;
    for (int l = 0; l < LL; ++l) {
        k_spmm<<<BB * NN, 64, 0, stream>>>((const float4*)hcur, row_ptr, col,
                                           (float4*)hnext);
        if (use_mfma) {
            k_gemm_mfma<<<(BB * NN / 128) * 2, 256, 0, stream>>>(
                hnext, wt_hi + (size_t)l * DD * DD, wt_lo + (size_t)l * DD * DD,
                b1 + l * DD, m_g + l * DD, m_b + l * DD, m_m + l * DD,
                m_v + l * DD, hcur);
            k_gemm_mfma<<<(BB * NN / 128) * 2, 256, 0, stream>>>(
                hcur, wt_hi + (size_t)(4 + l) * DD * DD,
                wt_lo + (size_t)(4 + l) * DD * DD,
                b2 + l * DD, g_g + l * DD, g_b + l * DD, g_m + l * DD,
                g_v + l * DD, hnext);
        } else {
            k_gemm_bn_relu<<<(BB * NN / 64) * 4, 256, 0, stream>>>(
                hnext, w1 + (size_t)l * DD * DD, b1 + l * DD, m_g + l * DD,
                m_b + l * DD, m_m + l * DD, m_v + l * DD, hcur);
            k_gemm_bn_relu<<<(BB * NN / 64) * 4, 256, 0, stream>>>(
                hcur, w2 + (size_t)l * DD * DD, b2 + l * DD, g_g + l * DD,
                g_b + l * DD, g_m + l * DD, g_v + l * DD, hnext);
        }
        k_score<<<BB * QQ, 64, 0, stream>>>((const float4*)hnext,
                                            (const float4*)pw, pb, l + 1, out);
        float* tmp = hcur; hcur = hnext; hnext = tmp;
    }
    k_sigmoid<<<1, 288, 0, stream>>>(out);
}

// Round 3
// 743.588 us; speedup vs baseline: 1.8454x; 1.0886x over previous
//
#include <hip/hip_runtime.h>
#include <hip/hip_bf16.h>

#define NN 2048
#define QQ 9
#define DD 256
#define LL 4
#define BB 32
#define EE 32768
#define EPSV 1e-5f

typedef __attribute__((ext_vector_type(8))) short bf16x8;
typedef __attribute__((ext_vector_type(4))) float f32x4;

__device__ __forceinline__ ushort f2bf(float x)
{
    uint u = __float_as_uint(x);
    u += 0x7FFFu + ((u >> 16) & 1u);
    return (ushort)(u >> 16);
}
__device__ __forceinline__ float bf2f(ushort h)
{
    return __uint_as_float(((uint)h) << 16);
}

// ---------- h0 planes = split(batch_feature with rows [0,Q) <- emotion_emb) ----------
__global__ void k_init2(const float4* __restrict__ bf, const float4* __restrict__ emo,
                        ushort4* __restrict__ hhi, ushort4* __restrict__ hlo)
{
    int total = BB * NN * (DD / 4);
    for (int idx = blockIdx.x * blockDim.x + threadIdx.x; idx < total;
         idx += gridDim.x * blockDim.x) {
        int d4 = idx & 63;
        int n  = (idx >> 6) & (NN - 1);
        float4 v = (n < QQ) ? emo[n * 64 + d4] : bf[idx];
        ushort4 h, l;
        h.x = f2bf(v.x); h.y = f2bf(v.y); h.z = f2bf(v.z); h.w = f2bf(v.w);
        l.x = f2bf(v.x - bf2f(h.x)); l.y = f2bf(v.y - bf2f(h.y));
        l.z = f2bf(v.z - bf2f(h.z)); l.w = f2bf(v.w - bf2f(h.w));
        hhi[idx] = h; hlo[idx] = l;
    }
}

// ---------- CSR build ----------
__global__ void k_count(const int* __restrict__ src, int* __restrict__ cnt)
{
    int e = blockIdx.x * blockDim.x + threadIdx.x;
    if (e < EE) atomicAdd(&cnt[src[e]], 1);
}

__global__ __launch_bounds__(256) void k_scan(const int* __restrict__ cnt,
                                              int* __restrict__ row_ptr,
                                              int* __restrict__ cursor)
{
    __shared__ int part[256];
    int t = threadIdx.x;
    int local[8];
    int s = 0;
    #pragma unroll
    for (int i = 0; i < 8; ++i) { local[i] = cnt[t * 8 + i]; s += local[i]; }
    part[t] = s;
    __syncthreads();
    for (int off = 1; off < 256; off <<= 1) {
        int v = (t >= off) ? part[t - off] : 0;
        __syncthreads();
        part[t] += v;
        __syncthreads();
    }
    int run = part[t] - s;
    #pragma unroll
    for (int i = 0; i < 8; ++i) {
        int idx = t * 8 + i;
        row_ptr[idx] = run;
        cursor[idx]  = run;
        run += local[i];
    }
    if (t == 255) row_ptr[NN] = run;
}

__global__ void k_fill(const int* __restrict__ src, const int* __restrict__ dst,
                       int* __restrict__ cursor, int* __restrict__ col)
{
    int e = blockIdx.x * blockDim.x + threadIdx.x;
    if (e < EE) {
        int p = atomicAdd(&cursor[src[e]], 1);
        col[p] = dst[e];
    }
}

// ---------- pooled = h + A.h  (split-plane in/out), XCD-partitioned ----------
__global__ __launch_bounds__(256) void k_spmm2(
    const ushort4* __restrict__ phi, const ushort4* __restrict__ plo,
    const int* __restrict__ row_ptr, const int* __restrict__ col,
    ushort4* __restrict__ ohi, ushort4* __restrict__ olo)
{
    // 16384 blocks; XCD x = bid%8 handles batches [4x, 4x+4): L2-resident slice
    int x  = blockIdx.x & 7;
    int rb = blockIdx.x >> 3;
    int w  = threadIdx.x >> 6;
    int t  = threadIdx.x & 63;
    int row = x * 8192 + rb * 4 + w;        // global row = b*NN + n
    int n = row & (NN - 1);
    const ushort4* hb_hi = phi + (size_t)(row - n) * 64;
    const ushort4* hb_lo = plo + (size_t)(row - n) * 64;

    ushort4 sh = hb_hi[(size_t)n * 64 + t];
    ushort4 sl = hb_lo[(size_t)n * 64 + t];
    float a0 = bf2f(sh.x) + bf2f(sl.x);
    float a1 = bf2f(sh.y) + bf2f(sl.y);
    float a2 = bf2f(sh.z) + bf2f(sl.z);
    float a3 = bf2f(sh.w) + bf2f(sl.w);

    int beg = row_ptr[n], end = row_ptr[n + 1];
    int j = beg;
    for (; j + 4 <= end; j += 4) {
        int c0 = col[j], c1 = col[j + 1], c2 = col[j + 2], c3 = col[j + 3];
        ushort4 h0 = hb_hi[(size_t)c0 * 64 + t], l0 = hb_lo[(size_t)c0 * 64 + t];
        ushort4 h1 = hb_hi[(size_t)c1 * 64 + t], l1 = hb_lo[(size_t)c1 * 64 + t];
        ushort4 h2 = hb_hi[(size_t)c2 * 64 + t], l2 = hb_lo[(size_t)c2 * 64 + t];
        ushort4 h3 = hb_hi[(size_t)c3 * 64 + t], l3 = hb_lo[(size_t)c3 * 64 + t];
        a0 += (bf2f(h0.x) + bf2f(l0.x)) + (bf2f(h1.x) + bf2f(l1.x)) +
              (bf2f(h2.x) + bf2f(l2.x)) + (bf2f(h3.x) + bf2f(l3.x));
        a1 += (bf2f(h0.y) + bf2f(l0.y)) + (bf2f(h1.y) + bf2f(l1.y)) +
              (bf2f(h2.y) + bf2f(l2.y)) + (bf2f(h3.y) + bf2f(l3.y));
        a2 += (bf2f(h0.z) + bf2f(l0.z)) + (bf2f(h1.z) + bf2f(l1.z)) +
              (bf2f(h2.z) + bf2f(l2.z)) + (bf2f(h3.z) + bf2f(l3.z));
        a3 += (bf2f(h0.w) + bf2f(l0.w)) + (bf2f(h1.w) + bf2f(l1.w)) +
              (bf2f(h2.w) + bf2f(l2.w)) + (bf2f(h3.w) + bf2f(l3.w));
    }
    for (; j < end; ++j) {
        int c = col[j];
        ushort4 hh = hb_hi[(size_t)c * 64 + t], ll = hb_lo[(size_t)c * 64 + t];
        a0 += bf2f(hh.x) + bf2f(ll.x);
        a1 += bf2f(hh.y) + bf2f(ll.y);
        a2 += bf2f(hh.z) + bf2f(ll.z);
        a3 += bf2f(hh.w) + bf2f(ll.w);
    }
    ushort4 oh, ol;
    oh.x = f2bf(a0); ol.x = f2bf(a0 - bf2f(oh.x));
    oh.y = f2bf(a1); ol.y = f2bf(a1 - bf2f(oh.y));
    oh.z = f2bf(a2); ol.z = f2bf(a2 - bf2f(oh.z));
    oh.w = f2bf(a3); ol.w = f2bf(a3 - bf2f(oh.w));
    size_t o = (size_t)row * 64 + t;
    ohi[o] = oh; olo[o] = ol;
}

// ---------- weight prep: Wt_hi/lo[mat][n][k] = split(W[mat][k][n]) ----------
__global__ __launch_bounds__(256) void k_wprep(const float* __restrict__ w1,
                                               const float* __restrict__ w2,
                                               ushort* __restrict__ wt_hi,
                                               ushort* __restrict__ wt_lo)
{
    __shared__ float tile[32][36];
    int bx = blockIdx.x;
    int mat = bx >> 6;
    int tt  = bx & 63;
    int tk = (tt >> 3) * 32;
    int tn = (tt & 7) * 32;
    const float* src = (mat < 4) ? (w1 + (size_t)mat * DD * DD)
                                 : (w2 + (size_t)(mat - 4) * DD * DD);
    int t = threadIdx.x;
    int r = t >> 3, c0 = (t & 7) * 4;
    float4 v = *(const float4*)(src + (size_t)(tk + r) * DD + tn + c0);
    tile[r][c0 + 0] = v.x; tile[r][c0 + 1] = v.y;
    tile[r][c0 + 2] = v.z; tile[r][c0 + 3] = v.w;
    __syncthreads();
    int nn = t >> 3, kq = (t & 7) * 4;
    ushort4 hh, ll;
    float x0 = tile[kq + 0][nn], x1 = tile[kq + 1][nn];
    float x2 = tile[kq + 2][nn], x3 = tile[kq + 3][nn];
    hh.x = f2bf(x0); hh.y = f2bf(x1); hh.z = f2bf(x2); hh.w = f2bf(x3);
    ll.x = f2bf(x0 - bf2f(hh.x)); ll.y = f2bf(x1 - bf2f(hh.y));
    ll.z = f2bf(x2 - bf2f(hh.z)); ll.w = f2bf(x3 - bf2f(hh.w));
    size_t off = (size_t)mat * DD * DD + (size_t)(tn + nn) * DD + tk + kq;
    *(ushort4*)(wt_hi + off) = hh;
    *(ushort4*)(wt_lo + off) = ll;
}

// ---------- MFMA split-bf16 GEMM, plane in / plane out ----------
__global__ __launch_bounds__(256) void k_gemm2(
    const ushort* __restrict__ Ahi, const ushort* __restrict__ Alo,
    const ushort* __restrict__ Whi, const ushort* __restrict__ Wlo,
    const float* __restrict__ bias, const float* __restrict__ gg,
    const float* __restrict__ bb, const float* __restrict__ mm,
    const float* __restrict__ vv,
    ushort* __restrict__ Ohi, ushort* __restrict__ Olo)
{
    __shared__ ushort As_hi[128][40];
    __shared__ ushort As_lo[128][40];
    __shared__ ushort Ws_hi[128][40];
    __shared__ ushort Ws_lo[128][40];
    int tid = threadIdx.x;
    int bm0 = (int)(blockIdx.x >> 1) * 128;
    int bn0 = (int)(blockIdx.x & 1) * 128;
    int lane = tid & 63;
    int w = tid >> 6;
    int wm = w & 1, wn = w >> 1;
    int lr = lane & 15, kg = lane >> 4;

    f32x4 acc[4][4];
    #pragma unroll
    for (int m = 0; m < 4; ++m)
        #pragma unroll
        for (int n = 0; n < 4; ++n) acc[m][n] = (f32x4)0.f;

    for (int kc = 0; kc < 8; ++kc) {
        int k0 = kc * 32;
        __syncthreads();
        #pragma unroll
        for (int i = 0; i < 2; ++i) {
            int idx = tid + i * 256;
            int r = idx >> 2, k8 = (idx & 3) * 8;
            size_t ga = (size_t)(bm0 + r) * DD + k0 + k8;
            size_t gw = (size_t)(bn0 + r) * DD + k0 + k8;
            *(float4*)&As_hi[r][k8] = *(const float4*)(Ahi + ga);
            *(float4*)&As_lo[r][k8] = *(const float4*)(Alo + ga);
            *(float4*)&Ws_hi[r][k8] = *(const float4*)(Whi + gw);
            *(float4*)&Ws_lo[r][k8] = *(const float4*)(Wlo + gw);
        }
        __syncthreads();
        bf16x8 ah[4], al[4], bh[4], bl[4];
        #pragma unroll
        for (int m = 0; m < 4; ++m) {
            ah[m] = *(const bf16x8*)&As_hi[wm * 64 + m * 16 + lr][kg * 8];
            al[m] = *(const bf16x8*)&As_lo[wm * 64 + m * 16 + lr][kg * 8];
        }
        #pragma unroll
        for (int n = 0; n < 4; ++n) {
            bh[n] = *(const bf16x8*)&Ws_hi[wn * 64 + n * 16 + lr][kg * 8];
            bl[n] = *(const bf16x8*)&Ws_lo[wn * 64 + n * 16 + lr][kg * 8];
        }
        #pragma unroll
        for (int m = 0; m < 4; ++m)
            #pragma unroll
            for (int n = 0; n < 4; ++n) {
                acc[m][n] = __builtin_amdgcn_mfma_f32_16x16x32_bf16(ah[m], bh[n], acc[m][n], 0, 0, 0);
                acc[m][n] = __builtin_amdgcn_mfma_f32_16x16x32_bf16(ah[m], bl[n], acc[m][n], 0, 0, 0);
                acc[m][n] = __builtin_amdgcn_mfma_f32_16x16x32_bf16(al[m], bh[n], acc[m][n], 0, 0, 0);
            }
    }
    int rg = lane >> 4;
    #pragma unroll
    for (int n = 0; n < 4; ++n) {
        int jj = bn0 + wn * 64 + n * 16 + lr;
        float s  = gg[jj] * rsqrtf(vv[jj] + EPSV);
        float sv = (bias[jj] - mm[jj]) * s + bb[jj];
        #pragma unroll
        for (int m = 0; m < 4; ++m) {
            int row0 = bm0 + wm * 64 + m * 16 + rg * 4;
            #pragma unroll
            for (int r = 0; r < 4; ++r) {
                float y = acc[m][n][r] * s + sv;
                y = y > 0.f ? y : 0.f;
                ushort h = f2bf(y);
                size_t o = (size_t)(row0 + r) * DD + jj;
                Ohi[o] = h;
                Olo[o] = f2bf(y - bf2f(h));
            }
        }
    }
}

// ---------- score[b,q] += h[b,q,:].pred_w[l] + pred_b[l] ----------
__global__ __launch_bounds__(64) void k_score2(const ushort4* __restrict__ hhi,
                                               const ushort4* __restrict__ hlo,
                                               const float4* __restrict__ pw,
                                               const float* __restrict__ pb, int l,
                                               float* __restrict__ out)
{
    int bid = blockIdx.x;
    int b = bid / QQ, q = bid % QQ;
    int t = threadIdx.x;
    size_t o = ((size_t)b * NN + q) * 64 + t;
    ushort4 hh = hhi[o], ll = hlo[o];
    float4 wv = pw[l * 64 + t];
    float sum = (bf2f(hh.x) + bf2f(ll.x)) * wv.x + (bf2f(hh.y) + bf2f(ll.y)) * wv.y +
                (bf2f(hh.z) + bf2f(ll.z)) * wv.z + (bf2f(hh.w) + bf2f(ll.w)) * wv.w;
    #pragma unroll
    for (int off = 32; off > 0; off >>= 1)
        sum += __shfl_down(sum, off);
    if (t == 0) out[bid] += sum + pb[l];
}

__global__ void k_sigmoid(float* out)
{
    int i = threadIdx.x + blockIdx.x * blockDim.x;
    if (i < BB * QQ) out[i] = 1.f / (1.f + expf(-out[i]));
}

extern "C" void kernel_launch(void* const* d_in, const int* in_sizes, int n_in,
                              void* d_out, int out_size, void* d_ws, size_t ws_size,
                              hipStream_t stream)
{
    const float* batch = (const float*)d_in[0];
    const int*   edges = (const int*)d_in[1];
    const float* emo   = (const float*)d_in[2];
    const float* w1    = (const float*)d_in[3];
    const float* b1    = (const float*)d_in[4];
    const float* m_g   = (const float*)d_in[5];
    const float* m_b   = (const float*)d_in[6];
    const float* m_m   = (const float*)d_in[7];
    const float* m_v   = (const float*)d_in[8];
    const float* w2    = (const float*)d_in[9];
    const float* b2    = (const float*)d_in[10];
    const float* g_g   = (const float*)d_in[11];
    const float* g_b   = (const float*)d_in[12];
    const float* g_m   = (const float*)d_in[13];
    const float* g_v   = (const float*)d_in[14];
    const float* pw    = (const float*)d_in[15];
    const float* pb    = (const float*)d_in[16];
    float* out = (float*)d_out;

    const size_t HSZ = (size_t)BB * NN * DD;   // 16,777,216 elements
    const size_t WT  = (size_t)8 * DD * DD;    // 524,288 elements

    ushort* pA_hi = (ushort*)d_ws;
    ushort* pA_lo = pA_hi + HSZ;
    ushort* pB_hi = pA_lo + HSZ;
    ushort* pB_lo = pB_hi + HSZ;
    ushort* wt_hi = pB_lo + HSZ;
    ushort* wt_lo = wt_hi + WT;
    int* cnt     = (int*)(wt_lo + WT);
    int* row_ptr = cnt + NN;
    int* cursor  = row_ptr + (NN + 1);
    int* col     = cursor + NN;

    const int* src = edges;
    const int* dst = edges + EE;

    hipMemsetAsync(cnt, 0, NN * sizeof(int), stream);
    hipMemsetAsync(d_out, 0, BB * QQ * sizeof(float), stream);
    k_init2<<<4096, 256, 0, stream>>>((const float4*)batch, (const float4*)emo,
                                      (ushort4*)pA_hi, (ushort4*)pA_lo);
    k_count<<<EE / 256, 256, 0, stream>>>(src, cnt);
    k_scan<<<1, 256, 0, stream>>>(cnt, row_ptr, cursor);
    k_fill<<<EE / 256, 256, 0, stream>>>(src, dst, cursor, col);
    k_wprep<<<512, 256, 0, stream>>>(w1, w2, wt_hi, wt_lo);
    k_score2<<<BB * QQ, 64, 0, stream>>>((const ushort4*)pA_hi, (const ushort4*)pA_lo,
                                         (const float4*)pw, pb, 0, out);

    ushort* cur_hi = pA_hi; ushort* cur_lo = pA_lo;
    ushort* nxt_hi = pB_hi; ushort* nxt_lo = pB_lo;
    for (int l = 0; l < LL; ++l) {
        k_spmm2<<<16384, 256, 0, stream>>>((const ushort4*)cur_hi, (const ushort4*)cur_lo,
                                           row_ptr, col,
                                           (ushort4*)nxt_hi, (ushort4*)nxt_lo);
        k_gemm2<<<1024, 256, 0, stream>>>(
            nxt_hi, nxt_lo, wt_hi + (size_t)l * DD * DD, wt_lo + (size_t)l * DD * DD,
            b1 + l * DD, m_g + l * DD, m_b + l * DD, m_m + l * DD, m_v + l * DD,
            cur_hi, cur_lo);
        k_gemm2<<<1024, 256, 0, stream>>>(
            cur_hi, cur_lo, wt_hi + (size_t)(4 + l) * DD * DD,
            wt_lo + (size_t)(4 + l) * DD * DD,
            b2 + l * DD, g_g + l * DD, g_b + l * DD, g_m + l * DD, g_v + l * DD,
            nxt_hi, nxt_lo);
        k_score2<<<BB * QQ, 64, 0, stream>>>((const ushort4*)nxt_hi, (const ushort4*)nxt_lo,
                                             (const float4*)pw, pb, l + 1, out);
        ushort* th = cur_hi; ushort* tl = cur_lo;
        cur_hi = nxt_hi; cur_lo = nxt_lo;
        nxt_hi = th;     nxt_lo = tl;
    }
    k_sigmoid<<<1, 288, 0, stream>>>(out);
}

// Round 4
// 654.361 us; speedup vs baseline: 2.0971x; 1.1364x over previous
//
#include <hip/hip_runtime.h>
#include <hip/hip_bf16.h>

#define NN 2048
#define QQ 9
#define DD 256
#define LL 4
#define BB 32
#define EE 32768
#define EPSV 1e-5f

typedef __attribute__((ext_vector_type(8))) short bf16x8;
typedef __attribute__((ext_vector_type(8))) ushort u16x8;
typedef __attribute__((ext_vector_type(4))) float f32x4;

__device__ __forceinline__ ushort f2bf(float x)
{
    uint u = __float_as_uint(x);
    u += 0x7FFFu + ((u >> 16) & 1u);
    return (ushort)(u >> 16);
}
__device__ __forceinline__ float bf2f(ushort h)
{
    return __uint_as_float(((uint)h) << 16);
}

// ---------- CSR build ----------
__global__ void k_count(const int* __restrict__ src, int* __restrict__ cnt)
{
    int e = blockIdx.x * blockDim.x + threadIdx.x;
    if (e < EE) atomicAdd(&cnt[src[e]], 1);
}

__global__ __launch_bounds__(256) void k_scan(const int* __restrict__ cnt,
                                              int* __restrict__ row_ptr,
                                              int* __restrict__ cursor)
{
    __shared__ int part[256];
    int t = threadIdx.x;
    int local[8];
    int s = 0;
    #pragma unroll
    for (int i = 0; i < 8; ++i) { local[i] = cnt[t * 8 + i]; s += local[i]; }
    part[t] = s;
    __syncthreads();
    for (int off = 1; off < 256; off <<= 1) {
        int v = (t >= off) ? part[t - off] : 0;
        __syncthreads();
        part[t] += v;
        __syncthreads();
    }
    int run = part[t] - s;
    #pragma unroll
    for (int i = 0; i < 8; ++i) {
        int idx = t * 8 + i;
        row_ptr[idx] = run;
        cursor[idx]  = run;
        run += local[i];
    }
    if (t == 255) row_ptr[NN] = run;
}

__global__ void k_fill(const int* __restrict__ src, const int* __restrict__ dst,
                       int* __restrict__ cursor, int* __restrict__ col)
{
    int e = blockIdx.x * blockDim.x + threadIdx.x;
    if (e < EE) {
        int p = atomicAdd(&cursor[src[e]], 1);
        col[p] = dst[e];
    }
}

// ---------- layer-0 SpMM: gather fp32 batch (emotion rows substituted) -> split planes ----------
__global__ __launch_bounds__(256) void k_spmm0(
    const float4* __restrict__ bat, const float4* __restrict__ emo,
    const int* __restrict__ row_ptr, const int* __restrict__ col,
    ushort4* __restrict__ ohi, ushort4* __restrict__ olo)
{
    int x  = blockIdx.x & 7;
    int rb = blockIdx.x >> 3;
    int w  = threadIdx.x >> 6;
    int t  = threadIdx.x & 63;
    int row = x * 8192 + rb * 4 + w;      // = b*NN + n
    int n = row & (NN - 1);
    const float4* bb4 = bat + (size_t)(row - n) * 64;   // batch-b base

    float4 own = (n < QQ) ? emo[n * 64 + t] : bb4[(size_t)n * 64 + t];
    float a0 = own.x, a1 = own.y, a2 = own.z, a3 = own.w;
    int beg = row_ptr[n], end = row_ptr[n + 1];
    int j = beg;
    for (; j + 8 <= end; j += 8) {
        float4 v[8];
        #pragma unroll
        for (int u = 0; u < 8; ++u) {
            int c = col[j + u];
            v[u] = (c < QQ) ? emo[c * 64 + t] : bb4[(size_t)c * 64 + t];
        }
        #pragma unroll
        for (int u = 0; u < 8; ++u) {
            a0 += v[u].x; a1 += v[u].y; a2 += v[u].z; a3 += v[u].w;
        }
    }
    for (; j < end; ++j) {
        int c = col[j];
        float4 v = (c < QQ) ? emo[c * 64 + t] : bb4[(size_t)c * 64 + t];
        a0 += v.x; a1 += v.y; a2 += v.z; a3 += v.w;
    }
    ushort4 oh, ol;
    oh.x = f2bf(a0); ol.x = f2bf(a0 - bf2f(oh.x));
    oh.y = f2bf(a1); ol.y = f2bf(a1 - bf2f(oh.y));
    oh.z = f2bf(a2); ol.z = f2bf(a2 - bf2f(oh.z));
    oh.w = f2bf(a3); ol.w = f2bf(a3 - bf2f(oh.w));
    size_t o = (size_t)row * 64 + t;
    ohi[o] = oh; olo[o] = ol;
}

// ---------- SpMM layers 1..3: lane-split hi/lo planes, unroll 8 ----------
__global__ __launch_bounds__(256) void k_spmm3(
    const ushort* __restrict__ phi, const ushort* __restrict__ plo,
    const int* __restrict__ row_ptr, const int* __restrict__ col,
    ushort* __restrict__ ohi, ushort* __restrict__ olo)
{
    int x  = blockIdx.x & 7;
    int rb = blockIdx.x >> 3;
    int w  = threadIdx.x >> 6;
    int t  = threadIdx.x & 63;
    int row = x * 8192 + rb * 4 + w;
    int n = row & (NN - 1);
    int half = t >> 5;        // 0: hi plane, 1: lo plane
    int c16  = t & 31;        // 16-byte chunk within row (32 chunks x 8 elems)
    const u16x8* bp = (const u16x8*)((half ? plo : phi) + (size_t)(row - n) * DD);

    u16x8 v = bp[n * 32 + c16];
    float a[8];
    #pragma unroll
    for (int k = 0; k < 8; ++k) a[k] = bf2f((ushort)v[k]);

    int beg = row_ptr[n], end = row_ptr[n + 1];
    int j = beg;
    for (; j + 8 <= end; j += 8) {
        u16x8 g[8];
        #pragma unroll
        for (int u = 0; u < 8; ++u)
            g[u] = bp[(size_t)col[j + u] * 32 + c16];
        #pragma unroll
        for (int u = 0; u < 8; ++u)
            #pragma unroll
            for (int k = 0; k < 8; ++k) a[k] += bf2f((ushort)g[u][k]);
    }
    for (; j < end; ++j) {
        u16x8 gv = bp[(size_t)col[j] * 32 + c16];
        #pragma unroll
        for (int k = 0; k < 8; ++k) a[k] += bf2f((ushort)gv[k]);
    }
    // combine hi-half and lo-half partial sums (identical bits on both lanes)
    #pragma unroll
    for (int k = 0; k < 8; ++k) a[k] += __shfl_xor(a[k], 32);

    u16x8 o;
    if (half == 0) {
        #pragma unroll
        for (int k = 0; k < 8; ++k) o[k] = f2bf(a[k]);
    } else {
        #pragma unroll
        for (int k = 0; k < 8; ++k) {
            ushort h = f2bf(a[k]);
            o[k] = f2bf(a[k] - bf2f(h));
        }
    }
    u16x8* op = (u16x8*)((half ? olo : ohi) + (size_t)row * DD);
    op[c16] = o;
}

// ---------- weight prep: Wt_hi/lo[mat][n][k] = split(W[mat][k][n]) ----------
__global__ __launch_bounds__(256) void k_wprep(const float* __restrict__ w1,
                                               const float* __restrict__ w2,
                                               ushort* __restrict__ wt_hi,
                                               ushort* __restrict__ wt_lo)
{
    __shared__ float tile[32][36];
    int bx = blockIdx.x;
    int mat = bx >> 6;
    int tt  = bx & 63;
    int tk = (tt >> 3) * 32;
    int tn = (tt & 7) * 32;
    const float* src = (mat < 4) ? (w1 + (size_t)mat * DD * DD)
                                 : (w2 + (size_t)(mat - 4) * DD * DD);
    int t = threadIdx.x;
    int r = t >> 3, c0 = (t & 7) * 4;
    float4 v = *(const float4*)(src + (size_t)(tk + r) * DD + tn + c0);
    tile[r][c0 + 0] = v.x; tile[r][c0 + 1] = v.y;
    tile[r][c0 + 2] = v.z; tile[r][c0 + 3] = v.w;
    __syncthreads();
    int nn = t >> 3, kq = (t & 7) * 4;
    ushort4 hh, ll;
    float x0 = tile[kq + 0][nn], x1 = tile[kq + 1][nn];
    float x2 = tile[kq + 2][nn], x3 = tile[kq + 3][nn];
    hh.x = f2bf(x0); hh.y = f2bf(x1); hh.z = f2bf(x2); hh.w = f2bf(x3);
    ll.x = f2bf(x0 - bf2f(hh.x)); ll.y = f2bf(x1 - bf2f(hh.y));
    ll.z = f2bf(x2 - bf2f(hh.z)); ll.w = f2bf(x3 - bf2f(hh.w));
    size_t off = (size_t)mat * DD * DD + (size_t)(tn + nn) * DD + tk + kq;
    *(ushort4*)(wt_hi + off) = hh;
    *(ushort4*)(wt_lo + off) = ll;
}

// ---------- MFMA split-bf16 GEMM with LDS-repacked coalesced epilogue ----------
__global__ __launch_bounds__(256) void k_gemm3(
    const ushort* __restrict__ Ahi, const ushort* __restrict__ Alo,
    const ushort* __restrict__ Whi, const ushort* __restrict__ Wlo,
    const float* __restrict__ bias, const float* __restrict__ gg,
    const float* __restrict__ bb, const float* __restrict__ mm,
    const float* __restrict__ vv,
    ushort* __restrict__ Ohi, ushort* __restrict__ Olo)
{
    __shared__ alignas(16) ushort SM[4 * 128 * 40];   // 40,960 B
    ushort (*As_hi)[40] = (ushort(*)[40])(SM);
    ushort (*As_lo)[40] = (ushort(*)[40])(SM + 5120);
    ushort (*Ws_hi)[40] = (ushort(*)[40])(SM + 10240);
    ushort (*Ws_lo)[40] = (ushort(*)[40])(SM + 15360);

    int tid = threadIdx.x;
    int bm0 = (int)(blockIdx.x >> 1) * 128;
    int bn0 = (int)(blockIdx.x & 1) * 128;
    int lane = tid & 63;
    int w = tid >> 6;
    int wm = w & 1, wn = w >> 1;
    int lr = lane & 15, kg = lane >> 4;

    f32x4 acc[4][4];
    #pragma unroll
    for (int m = 0; m < 4; ++m)
        #pragma unroll
        for (int n = 0; n < 4; ++n) acc[m][n] = (f32x4)0.f;

    for (int kc = 0; kc < 8; ++kc) {
        int k0 = kc * 32;
        __syncthreads();
        #pragma unroll
        for (int i = 0; i < 2; ++i) {
            int idx = tid + i * 256;
            int r = idx >> 2, k8 = (idx & 3) * 8;
            size_t ga = (size_t)(bm0 + r) * DD + k0 + k8;
            size_t gw = (size_t)(bn0 + r) * DD + k0 + k8;
            *(float4*)&As_hi[r][k8] = *(const float4*)(Ahi + ga);
            *(float4*)&As_lo[r][k8] = *(const float4*)(Alo + ga);
            *(float4*)&Ws_hi[r][k8] = *(const float4*)(Whi + gw);
            *(float4*)&Ws_lo[r][k8] = *(const float4*)(Wlo + gw);
        }
        __syncthreads();
        bf16x8 ah[4], al[4], bh[4], bl[4];
        #pragma unroll
        for (int m = 0; m < 4; ++m) {
            ah[m] = *(const bf16x8*)&As_hi[wm * 64 + m * 16 + lr][kg * 8];
            al[m] = *(const bf16x8*)&As_lo[wm * 64 + m * 16 + lr][kg * 8];
        }
        #pragma unroll
        for (int n = 0; n < 4; ++n) {
            bh[n] = *(const bf16x8*)&Ws_hi[wn * 64 + n * 16 + lr][kg * 8];
            bl[n] = *(const bf16x8*)&Ws_lo[wn * 64 + n * 16 + lr][kg * 8];
        }
        #pragma unroll
        for (int m = 0; m < 4; ++m)
            #pragma unroll
            for (int n = 0; n < 4; ++n) {
                acc[m][n] = __builtin_amdgcn_mfma_f32_16x16x32_bf16(ah[m], bh[n], acc[m][n], 0, 0, 0);
                acc[m][n] = __builtin_amdgcn_mfma_f32_16x16x32_bf16(ah[m], bl[n], acc[m][n], 0, 0, 0);
                acc[m][n] = __builtin_amdgcn_mfma_f32_16x16x32_bf16(al[m], bh[n], acc[m][n], 0, 0, 0);
            }
    }

    // ---- epilogue: BN+ReLU, repack via per-wave LDS scratch, 16B stores ----
    __syncthreads();                       // staging LDS now reusable
    float* ep = (float*)SM + (size_t)w * (16 * 68);   // [16 rows][68] f32 per wave
    float sN[4], svN[4];
    #pragma unroll
    for (int n = 0; n < 4; ++n) {
        int jj = bn0 + wn * 64 + n * 16 + lr;
        sN[n]  = gg[jj] * rsqrtf(vv[jj] + EPSV);
        svN[n] = (bias[jj] - mm[jj]) * sN[n] + bb[jj];
    }
    int rg = lane >> 4;
    int rl = lane >> 2;            // read row 0..15
    int cb = (lane & 3) * 16;      // read col base
    #pragma unroll
    for (int m = 0; m < 4; ++m) {
        #pragma unroll
        for (int n = 0; n < 4; ++n) {
            int cc = n * 16 + lr;
            #pragma unroll
            for (int r = 0; r < 4; ++r) {
                float y = acc[m][n][r] * sN[n] + svN[n];
                ep[(rg * 4 + r) * 68 + cc] = y > 0.f ? y : 0.f;
            }
        }
        // wave-private region: in-order DS + compiler waitcnt give visibility
        f32x4 v0 = *(const f32x4*)&ep[rl * 68 + cb + 0];
        f32x4 v1 = *(const f32x4*)&ep[rl * 68 + cb + 4];
        f32x4 v2 = *(const f32x4*)&ep[rl * 68 + cb + 8];
        f32x4 v3 = *(const f32x4*)&ep[rl * 68 + cb + 12];
        u16x8 hh0, ll0, hh1, ll1;
        #pragma unroll
        for (int c = 0; c < 4; ++c) {
            ushort h;
            h = f2bf(v0[c]); hh0[c] = h;     ll0[c] = f2bf(v0[c] - bf2f(h));
            h = f2bf(v1[c]); hh0[4 + c] = h; ll0[4 + c] = f2bf(v1[c] - bf2f(h));
            h = f2bf(v2[c]); hh1[c] = h;     ll1[c] = f2bf(v2[c] - bf2f(h));
            h = f2bf(v3[c]); hh1[4 + c] = h; ll1[4 + c] = f2bf(v3[c] - bf2f(h));
        }
        size_t o = (size_t)(bm0 + wm * 64 + m * 16 + rl) * DD + bn0 + wn * 64 + cb;
        *(u16x8*)(Ohi + o) = hh0;
        *(u16x8*)(Ohi + o + 8) = hh1;
        *(u16x8*)(Olo + o) = ll0;
        *(u16x8*)(Olo + o + 8) = ll1;
    }
}

// ---------- layer-0 score: batch-independent (h0 emotion rows == emotion_emb) ----------
__global__ __launch_bounds__(64) void k_score0(const float4* __restrict__ emo,
                                               const float4* __restrict__ pw,
                                               const float* __restrict__ pb,
                                               float* __restrict__ out)
{
    int q = blockIdx.x, t = threadIdx.x;
    float4 e = emo[q * 64 + t], wv = pw[t];
    float s = e.x * wv.x + e.y * wv.y + e.z * wv.z + e.w * wv.w;
    #pragma unroll
    for (int off = 32; off > 0; off >>= 1) s += __shfl_down(s, off);
    if (t == 0) {
        s += pb[0];
        for (int b = 0; b < BB; ++b) out[b * QQ + q] += s;
    }
}

// ---------- score layers 1..4 ----------
__global__ __launch_bounds__(64) void k_score2(const ushort4* __restrict__ hhi,
                                               const ushort4* __restrict__ hlo,
                                               const float4* __restrict__ pw,
                                               const float* __restrict__ pb, int l,
                                               float* __restrict__ out)
{
    int bid = blockIdx.x;
    int b = bid / QQ, q = bid % QQ;
    int t = threadIdx.x;
    size_t o = ((size_t)b * NN + q) * 64 + t;
    ushort4 hh = hhi[o], ll = hlo[o];
    float4 wv = pw[l * 64 + t];
    float sum = (bf2f(hh.x) + bf2f(ll.x)) * wv.x + (bf2f(hh.y) + bf2f(ll.y)) * wv.y +
                (bf2f(hh.z) + bf2f(ll.z)) * wv.z + (bf2f(hh.w) + bf2f(ll.w)) * wv.w;
    #pragma unroll
    for (int off = 32; off > 0; off >>= 1) sum += __shfl_down(sum, off);
    if (t == 0) out[bid] += sum + pb[l];
}

__global__ void k_sigmoid(float* out)
{
    int i = threadIdx.x + blockIdx.x * blockDim.x;
    if (i < BB * QQ) out[i] = 1.f / (1.f + expf(-out[i]));
}

extern "C" void kernel_launch(void* const* d_in, const int* in_sizes, int n_in,
                              void* d_out, int out_size, void* d_ws, size_t ws_size,
                              hipStream_t stream)
{
    const float* batch = (const float*)d_in[0];
    const int*   edges = (const int*)d_in[1];
    const float* emo   = (const float*)d_in[2];
    const float* w1    = (const float*)d_in[3];
    const float* b1    = (const float*)d_in[4];
    const float* m_g   = (const float*)d_in[5];
    const float* m_b   = (const float*)d_in[6];
    const float* m_m   = (const float*)d_in[7];
    const float* m_v   = (const float*)d_in[8];
    const float* w2    = (const float*)d_in[9];
    const float* b2    = (const float*)d_in[10];
    const float* g_g   = (const float*)d_in[11];
    const float* g_b   = (const float*)d_in[12];
    const float* g_m   = (const float*)d_in[13];
    const float* g_v   = (const float*)d_in[14];
    const float* pw    = (const float*)d_in[15];
    const float* pb    = (const float*)d_in[16];
    float* out = (float*)d_out;

    const size_t HSZ = (size_t)BB * NN * DD;
    const size_t WT  = (size_t)8 * DD * DD;

    ushort* pA_hi = (ushort*)d_ws;
    ushort* pA_lo = pA_hi + HSZ;
    ushort* pB_hi = pA_lo + HSZ;
    ushort* pB_lo = pB_hi + HSZ;
    ushort* wt_hi = pB_lo + HSZ;
    ushort* wt_lo = wt_hi + WT;
    int* cnt     = (int*)(wt_lo + WT);
    int* row_ptr = cnt + NN;
    int* cursor  = row_ptr + (NN + 1);
    int* col     = cursor + NN;

    const int* src = edges;
    const int* dst = edges + EE;

    hipMemsetAsync(cnt, 0, NN * sizeof(int), stream);
    hipMemsetAsync(d_out, 0, BB * QQ * sizeof(float), stream);
    k_count<<<EE / 256, 256, 0, stream>>>(src, cnt);
    k_scan<<<1, 256, 0, stream>>>(cnt, row_ptr, cursor);
    k_fill<<<EE / 256, 256, 0, stream>>>(src, dst, cursor, col);
    k_wprep<<<512, 256, 0, stream>>>(w1, w2, wt_hi, wt_lo);
    k_score0<<<QQ, 64, 0, stream>>>((const float4*)emo, (const float4*)pw, pb, out);

    // layer 0: pooled0 directly from fp32 batch (+emotion substitution) -> pair A
    k_spmm0<<<16384, 256, 0, stream>>>((const float4*)batch, (const float4*)emo,
                                       row_ptr, col,
                                       (ushort4*)pA_hi, (ushort4*)pA_lo);

    ushort* cur_hi = pA_hi; ushort* cur_lo = pA_lo;
    ushort* nxt_hi = pB_hi; ushort* nxt_lo = pB_lo;
    for (int l = 0; l < LL; ++l) {
        if (l > 0) {
            // pooled_l = spmm(h_l): cur -> nxt, then swap roles inside GEMMs
            k_spmm3<<<16384, 256, 0, stream>>>(cur_hi, cur_lo, row_ptr, col,
                                               nxt_hi, nxt_lo);
            ushort* th = cur_hi; ushort* tl = cur_lo;
            cur_hi = nxt_hi; cur_lo = nxt_lo;
            nxt_hi = th;     nxt_lo = tl;
        }
        // cur holds pooled; t = gemm1(pooled) -> nxt ; h = gemm2(t) -> cur
        k_gemm3<<<1024, 256, 0, stream>>>(
            cur_hi, cur_lo, wt_hi + (size_t)l * DD * DD, wt_lo + (size_t)l * DD * DD,
            b1 + l * DD, m_g + l * DD, m_b + l * DD, m_m + l * DD, m_v + l * DD,
            nxt_hi, nxt_lo);
        k_gemm3<<<1024, 256, 0, stream>>>(
            nxt_hi, nxt_lo, wt_hi + (size_t)(4 + l) * DD * DD,
            wt_lo + (size_t)(4 + l) * DD * DD,
            b2 + l * DD, g_g + l * DD, g_b + l * DD, g_m + l * DD, g_v + l * DD,
            cur_hi, cur_lo);
        k_score2<<<BB * QQ, 64, 0, stream>>>((const ushort4*)cur_hi,
                                             (const ushort4*)cur_lo,
                                             (const float4*)pw, pb, l + 1, out);
    }
    k_sigmoid<<<1, 288, 0, stream>>>(out);
}

// Round 5
// 521.060 us; speedup vs baseline: 2.6336x; 1.2558x over previous
//
#include <hip/hip_runtime.h>
#include <hip/hip_bf16.h>

#define NN 2048
#define QQ 9
#define DD 256
#define LL 4
#define BB 32
#define EE 32768
#define EPSV 1e-5f

typedef __attribute__((ext_vector_type(8))) short bf16x8;
typedef __attribute__((ext_vector_type(8))) ushort u16x8;
typedef __attribute__((ext_vector_type(4))) float f32x4;
typedef __attribute__((ext_vector_type(4))) int i32x4;

__device__ __forceinline__ ushort f2bf(float x)
{
    uint u = __float_as_uint(x);
    u += 0x7FFFu + ((u >> 16) & 1u);
    return (ushort)(u >> 16);
}
__device__ __forceinline__ float bf2f(ushort h)
{
    return __uint_as_float(((uint)h) << 16);
}

// ---------- CSR build ----------
__global__ void k_count(const int* __restrict__ src, int* __restrict__ cnt)
{
    int e = blockIdx.x * blockDim.x + threadIdx.x;
    if (e < EE) atomicAdd(&cnt[src[e]], 1);
}

__global__ __launch_bounds__(256) void k_scan(const int* __restrict__ cnt,
                                              int* __restrict__ row_ptr,
                                              int* __restrict__ cursor)
{
    __shared__ int part[256];
    int t = threadIdx.x;
    int local[8];
    int s = 0;
    #pragma unroll
    for (int i = 0; i < 8; ++i) { local[i] = cnt[t * 8 + i]; s += local[i]; }
    part[t] = s;
    __syncthreads();
    for (int off = 1; off < 256; off <<= 1) {
        int v = (t >= off) ? part[t - off] : 0;
        __syncthreads();
        part[t] += v;
        __syncthreads();
    }
    int run = part[t] - s;
    #pragma unroll
    for (int i = 0; i < 8; ++i) {
        int idx = t * 8 + i;
        row_ptr[idx] = run;
        cursor[idx]  = run;
        run += local[i];
    }
    if (t == 255) row_ptr[NN] = run;
}

__global__ void k_fill(const int* __restrict__ src, const int* __restrict__ dst,
                       int* __restrict__ cursor, int* __restrict__ col)
{
    int e = blockIdx.x * blockDim.x + threadIdx.x;
    if (e < EE) {
        int p = atomicAdd(&cursor[src[e]], 1);
        col[p] = dst[e];
    }
}

// ---------- h0 hi-plane = bf16(batch with rows [0,Q) <- emotion_emb) ----------
__global__ void k_prep0(const float4* __restrict__ bf, const float4* __restrict__ emo,
                        ushort4* __restrict__ hhi)
{
    int total = BB * NN * (DD / 4);
    for (int idx = blockIdx.x * blockDim.x + threadIdx.x; idx < total;
         idx += gridDim.x * blockDim.x) {
        int d4 = idx & 63;
        int n  = (idx >> 6) & (NN - 1);
        float4 v = (n < QQ) ? emo[n * 64 + d4] : bf[idx];
        ushort4 h;
        h.x = f2bf(v.x); h.y = f2bf(v.y); h.z = f2bf(v.z); h.w = f2bf(v.w);
        hhi[idx] = h;
    }
}

// ---------- pooled = h + A.h : hi-only gather, f32 accumulate, hi+lo output ----------
__global__ __launch_bounds__(256) void k_spmm4(
    const ushort* __restrict__ phi,
    const int* __restrict__ row_ptr, const int* __restrict__ col,
    ushort* __restrict__ ohi, ushort* __restrict__ olo)
{
    int x  = blockIdx.x & 7;             // XCD slice: batches [4x, 4x+4)
    int rb = blockIdx.x >> 3;
    int w  = threadIdx.x >> 6;
    int t  = threadIdx.x & 63;           // lane owns elements [4t, 4t+4)
    int row = x * 8192 + rb * 4 + w;     // = b*NN + n
    int n = row & (NN - 1);
    const ushort4* hb = (const ushort4*)(phi + (size_t)(row - n) * DD);

    ushort4 sv = hb[(size_t)n * 64 + t];
    float a0 = bf2f(sv.x), a1 = bf2f(sv.y), a2 = bf2f(sv.z), a3 = bf2f(sv.w);

    int beg = row_ptr[n], end = row_ptr[n + 1];
    int j = beg;
    // align j to 4 for vector col loads (col base is 16B-aligned)
    for (; j < end && (j & 3); ++j) {
        ushort4 g = hb[(size_t)col[j] * 64 + t];
        a0 += bf2f(g.x); a1 += bf2f(g.y); a2 += bf2f(g.z); a3 += bf2f(g.w);
    }
    for (; j + 8 <= end; j += 8) {
        i32x4 c0 = *(const i32x4*)(col + j);
        i32x4 c1 = *(const i32x4*)(col + j + 4);
        ushort4 g[8];
        g[0] = hb[(size_t)c0.x * 64 + t];
        g[1] = hb[(size_t)c0.y * 64 + t];
        g[2] = hb[(size_t)c0.z * 64 + t];
        g[3] = hb[(size_t)c0.w * 64 + t];
        g[4] = hb[(size_t)c1.x * 64 + t];
        g[5] = hb[(size_t)c1.y * 64 + t];
        g[6] = hb[(size_t)c1.z * 64 + t];
        g[7] = hb[(size_t)c1.w * 64 + t];
        #pragma unroll
        for (int u = 0; u < 8; ++u) {
            a0 += bf2f(g[u].x); a1 += bf2f(g[u].y);
            a2 += bf2f(g[u].z); a3 += bf2f(g[u].w);
        }
    }
    if (j + 4 <= end) {
        i32x4 c = *(const i32x4*)(col + j);
        ushort4 g[4];
        g[0] = hb[(size_t)c.x * 64 + t];
        g[1] = hb[(size_t)c.y * 64 + t];
        g[2] = hb[(size_t)c.z * 64 + t];
        g[3] = hb[(size_t)c.w * 64 + t];
        #pragma unroll
        for (int u = 0; u < 4; ++u) {
            a0 += bf2f(g[u].x); a1 += bf2f(g[u].y);
            a2 += bf2f(g[u].z); a3 += bf2f(g[u].w);
        }
        j += 4;
    }
    for (; j < end; ++j) {
        ushort4 g = hb[(size_t)col[j] * 64 + t];
        a0 += bf2f(g.x); a1 += bf2f(g.y); a2 += bf2f(g.z); a3 += bf2f(g.w);
    }

    ushort4 oh, ol;
    oh.x = f2bf(a0); ol.x = f2bf(a0 - bf2f(oh.x));
    oh.y = f2bf(a1); ol.y = f2bf(a1 - bf2f(oh.y));
    oh.z = f2bf(a2); ol.z = f2bf(a2 - bf2f(oh.z));
    oh.w = f2bf(a3); ol.w = f2bf(a3 - bf2f(oh.w));
    ((ushort4*)(ohi + (size_t)row * DD))[t] = oh;
    ((ushort4*)(olo + (size_t)row * DD))[t] = ol;
}

// ---------- weight prep: Wt_hi/lo[mat][n][k] = split(W[mat][k][n]) ----------
__global__ __launch_bounds__(256) void k_wprep(const float* __restrict__ w1,
                                               const float* __restrict__ w2,
                                               ushort* __restrict__ wt_hi,
                                               ushort* __restrict__ wt_lo)
{
    __shared__ float tile[32][36];
    int bx = blockIdx.x;
    int mat = bx >> 6;
    int tt  = bx & 63;
    int tk = (tt >> 3) * 32;
    int tn = (tt & 7) * 32;
    const float* src = (mat < 4) ? (w1 + (size_t)mat * DD * DD)
                                 : (w2 + (size_t)(mat - 4) * DD * DD);
    int t = threadIdx.x;
    int r = t >> 3, c0 = (t & 7) * 4;
    float4 v = *(const float4*)(src + (size_t)(tk + r) * DD + tn + c0);
    tile[r][c0 + 0] = v.x; tile[r][c0 + 1] = v.y;
    tile[r][c0 + 2] = v.z; tile[r][c0 + 3] = v.w;
    __syncthreads();
    int nn = t >> 3, kq = (t & 7) * 4;
    ushort4 hh, ll;
    float x0 = tile[kq + 0][nn], x1 = tile[kq + 1][nn];
    float x2 = tile[kq + 2][nn], x3 = tile[kq + 3][nn];
    hh.x = f2bf(x0); hh.y = f2bf(x1); hh.z = f2bf(x2); hh.w = f2bf(x3);
    ll.x = f2bf(x0 - bf2f(hh.x)); ll.y = f2bf(x1 - bf2f(hh.y));
    ll.z = f2bf(x2 - bf2f(hh.z)); ll.w = f2bf(x3 - bf2f(hh.w));
    size_t off = (size_t)mat * DD * DD + (size_t)(tn + nn) * DD + tk + kq;
    *(ushort4*)(wt_hi + off) = hh;
    *(ushort4*)(wt_lo + off) = ll;
}

// ---------- MFMA GEMM: O_hi = bf16(relu(bn(A @ W + bias))) ----------
// ALO=1: A has hi+lo planes (3 MFMA); ALO=0: A hi-only (2 MFMA)
template <int ALO>
__global__ __launch_bounds__(256) void k_gemm4(
    const ushort* __restrict__ Ahi, const ushort* __restrict__ Alo,
    const ushort* __restrict__ Whi, const ushort* __restrict__ Wlo,
    const float* __restrict__ bias, const float* __restrict__ gg,
    const float* __restrict__ bb, const float* __restrict__ mm,
    const float* __restrict__ vv,
    ushort* __restrict__ Ohi)
{
    constexpr int PLANES = ALO ? 4 : 3;
    __shared__ alignas(16) ushort SM[PLANES * 5120];     // 128x40 ushorts/plane
    ushort (*As_hi)[40] = (ushort(*)[40])(SM);
    ushort (*As_lo)[40] = (ushort(*)[40])(SM + (ALO ? 5120 : 0));
    ushort (*Ws_hi)[40] = (ushort(*)[40])(SM + (ALO ? 10240 : 5120));
    ushort (*Ws_lo)[40] = (ushort(*)[40])(SM + (ALO ? 15360 : 10240));

    int tid = threadIdx.x;
    int bm0 = (int)(blockIdx.x >> 1) * 128;
    int bn0 = (int)(blockIdx.x & 1) * 128;
    int lane = tid & 63;
    int w = tid >> 6;
    int wm = w & 1, wn = w >> 1;
    int lr = lane & 15, kg = lane >> 4;

    f32x4 acc[4][4];
    #pragma unroll
    for (int m = 0; m < 4; ++m)
        #pragma unroll
        for (int n = 0; n < 4; ++n) acc[m][n] = (f32x4)0.f;

    for (int kc = 0; kc < 8; ++kc) {
        int k0 = kc * 32;
        __syncthreads();
        #pragma unroll
        for (int i = 0; i < 2; ++i) {
            int idx = tid + i * 256;
            int r = idx >> 2, k8 = (idx & 3) * 8;
            size_t ga = (size_t)(bm0 + r) * DD + k0 + k8;
            size_t gw = (size_t)(bn0 + r) * DD + k0 + k8;
            *(float4*)&As_hi[r][k8] = *(const float4*)(Ahi + ga);
            if (ALO)
                *(float4*)&As_lo[r][k8] = *(const float4*)(Alo + ga);
            *(float4*)&Ws_hi[r][k8] = *(const float4*)(Whi + gw);
            *(float4*)&Ws_lo[r][k8] = *(const float4*)(Wlo + gw);
        }
        __syncthreads();
        bf16x8 ah[4], al[4], bh[4], bl[4];
        #pragma unroll
        for (int m = 0; m < 4; ++m) {
            ah[m] = *(const bf16x8*)&As_hi[wm * 64 + m * 16 + lr][kg * 8];
            if (ALO)
                al[m] = *(const bf16x8*)&As_lo[wm * 64 + m * 16 + lr][kg * 8];
        }
        #pragma unroll
        for (int n = 0; n < 4; ++n) {
            bh[n] = *(const bf16x8*)&Ws_hi[wn * 64 + n * 16 + lr][kg * 8];
            bl[n] = *(const bf16x8*)&Ws_lo[wn * 64 + n * 16 + lr][kg * 8];
        }
        #pragma unroll
        for (int m = 0; m < 4; ++m)
            #pragma unroll
            for (int n = 0; n < 4; ++n) {
                acc[m][n] = __builtin_amdgcn_mfma_f32_16x16x32_bf16(ah[m], bh[n], acc[m][n], 0, 0, 0);
                acc[m][n] = __builtin_amdgcn_mfma_f32_16x16x32_bf16(ah[m], bl[n], acc[m][n], 0, 0, 0);
                if (ALO)
                    acc[m][n] = __builtin_amdgcn_mfma_f32_16x16x32_bf16(al[m], bh[n], acc[m][n], 0, 0, 0);
            }
    }

    // ---- epilogue: BN+ReLU, repack via per-wave LDS scratch, 16B hi stores ----
    __syncthreads();
    float* ep = (float*)SM + (size_t)w * (16 * 68);
    float sN[4], svN[4];
    #pragma unroll
    for (int n = 0; n < 4; ++n) {
        int jj = bn0 + wn * 64 + n * 16 + lr;
        sN[n]  = gg[jj] * rsqrtf(vv[jj] + EPSV);
        svN[n] = (bias[jj] - mm[jj]) * sN[n] + bb[jj];
    }
    int rg = lane >> 4;
    int rl = lane >> 2;
    int cb = (lane & 3) * 16;
    #pragma unroll
    for (int m = 0; m < 4; ++m) {
        #pragma unroll
        for (int n = 0; n < 4; ++n) {
            int cc = n * 16 + lr;
            #pragma unroll
            for (int r = 0; r < 4; ++r) {
                float y = acc[m][n][r] * sN[n] + svN[n];
                ep[(rg * 4 + r) * 68 + cc] = y > 0.f ? y : 0.f;
            }
        }
        f32x4 v0 = *(const f32x4*)&ep[rl * 68 + cb + 0];
        f32x4 v1 = *(const f32x4*)&ep[rl * 68 + cb + 4];
        f32x4 v2 = *(const f32x4*)&ep[rl * 68 + cb + 8];
        f32x4 v3 = *(const f32x4*)&ep[rl * 68 + cb + 12];
        u16x8 hh0, hh1;
        #pragma unroll
        for (int c = 0; c < 4; ++c) {
            hh0[c]     = f2bf(v0[c]);
            hh0[4 + c] = f2bf(v1[c]);
            hh1[c]     = f2bf(v2[c]);
            hh1[4 + c] = f2bf(v3[c]);
        }
        size_t o = (size_t)(bm0 + wm * 64 + m * 16 + rl) * DD + bn0 + wn * 64 + cb;
        *(u16x8*)(Ohi + o) = hh0;
        *(u16x8*)(Ohi + o + 8) = hh1;
    }
}

// ---------- layer-0 score: batch-independent; ASSIGNS output ----------
__global__ __launch_bounds__(64) void k_score0(const float4* __restrict__ emo,
                                               const float4* __restrict__ pw,
                                               const float* __restrict__ pb,
                                               float* __restrict__ out)
{
    int q = blockIdx.x, t = threadIdx.x;
    float4 e = emo[q * 64 + t], wv = pw[t];
    float s = e.x * wv.x + e.y * wv.y + e.z * wv.z + e.w * wv.w;
    #pragma unroll
    for (int off = 32; off > 0; off >>= 1) s += __shfl_down(s, off);
    if (t == 0) {
        s += pb[0];
        for (int b = 0; b < BB; ++b) out[b * QQ + q] = s;
    }
}

// ---------- score layers 1..4 (hi plane only) ----------
__global__ __launch_bounds__(64) void k_score2(const ushort4* __restrict__ hhi,
                                               const float4* __restrict__ pw,
                                               const float* __restrict__ pb, int l,
                                               float* __restrict__ out)
{
    int bid = blockIdx.x;
    int b = bid / QQ, q = bid % QQ;
    int t = threadIdx.x;
    size_t o = ((size_t)b * NN + q) * 64 + t;
    ushort4 hh = hhi[o];
    float4 wv = pw[l * 64 + t];
    float sum = bf2f(hh.x) * wv.x + bf2f(hh.y) * wv.y +
                bf2f(hh.z) * wv.z + bf2f(hh.w) * wv.w;
    #pragma unroll
    for (int off = 32; off > 0; off >>= 1) sum += __shfl_down(sum, off);
    if (t == 0) out[bid] += sum + pb[l];
}

__global__ void k_sigmoid(float* out)
{
    int i = threadIdx.x + blockIdx.x * blockDim.x;
    if (i < BB * QQ) out[i] = 1.f / (1.f + expf(-out[i]));
}

extern "C" void kernel_launch(void* const* d_in, const int* in_sizes, int n_in,
                              void* d_out, int out_size, void* d_ws, size_t ws_size,
                              hipStream_t stream)
{
    const float* batch = (const float*)d_in[0];
    const int*   edges = (const int*)d_in[1];
    const float* emo   = (const float*)d_in[2];
    const float* w1    = (const float*)d_in[3];
    const float* b1    = (const float*)d_in[4];
    const float* m_g   = (const float*)d_in[5];
    const float* m_b   = (const float*)d_in[6];
    const float* m_m   = (const float*)d_in[7];
    const float* m_v   = (const float*)d_in[8];
    const float* w2    = (const float*)d_in[9];
    const float* b2    = (const float*)d_in[10];
    const float* g_g   = (const float*)d_in[11];
    const float* g_b   = (const float*)d_in[12];
    const float* g_m   = (const float*)d_in[13];
    const float* g_v   = (const float*)d_in[14];
    const float* pw    = (const float*)d_in[15];
    const float* pb    = (const float*)d_in[16];
    float* out = (float*)d_out;

    const size_t HSZ = (size_t)BB * NN * DD;   // elements per plane
    const size_t WT  = (size_t)8 * DD * DD;

    ushort* h_hi = (ushort*)d_ws;          // current hidden state (hi only)
    ushort* P_hi = h_hi + HSZ;             // pooled hi
    ushort* P_lo = P_hi + HSZ;             // pooled lo
    ushort* T_hi = P_lo + HSZ;             // mid activation t (hi only)
    ushort* wt_hi = T_hi + HSZ;
    ushort* wt_lo = wt_hi + WT;
    int* cnt     = (int*)(wt_lo + WT);     // 2048
    int* row_ptr = cnt + NN;               // 2049 used, padded to 2052
    int* cursor  = row_ptr + (NN + 4);     // 2048
    int* col     = cursor + NN;            // 32768, 16B-aligned

    const int* src = edges;
    const int* dst = edges + EE;

    hipMemsetAsync(cnt, 0, NN * sizeof(int), stream);
    k_count<<<EE / 256, 256, 0, stream>>>(src, cnt);
    k_scan<<<1, 256, 0, stream>>>(cnt, row_ptr, cursor);
    k_fill<<<EE / 256, 256, 0, stream>>>(src, dst, cursor, col);
    k_wprep<<<512, 256, 0, stream>>>(w1, w2, wt_hi, wt_lo);
    k_prep0<<<4096, 256, 0, stream>>>((const float4*)batch, (const float4*)emo,
                                      (ushort4*)h_hi);
    k_score0<<<QQ, 64, 0, stream>>>((const float4*)emo, (const float4*)pw, pb, out);

    for (int l = 0; l < LL; ++l) {
        // pooled = h + A.h  (hi-only gather, hi+lo out)
        k_spmm4<<<16384, 256, 0, stream>>>(h_hi, row_ptr, col, P_hi, P_lo);
        // t = relu(bn1(pooled @ w1 + b1)) : 3-MFMA, hi-only out
        k_gemm4<1><<<1024, 256, 0, stream>>>(
            P_hi, P_lo, wt_hi + (size_t)l * DD * DD, wt_lo + (size_t)l * DD * DD,
            b1 + l * DD, m_g + l * DD, m_b + l * DD, m_m + l * DD, m_v + l * DD,
            T_hi);
        // h = relu(bn2(t @ w2 + b2)) : 2-MFMA, hi-only out
        k_gemm4<0><<<1024, 256, 0, stream>>>(
            T_hi, nullptr, wt_hi + (size_t)(4 + l) * DD * DD,
            wt_lo + (size_t)(4 + l) * DD * DD,
            b2 + l * DD, g_g + l * DD, g_b + l * DD, g_m + l * DD, g_v + l * DD,
            h_hi);
        k_score2<<<BB * QQ, 64, 0, stream>>>((const ushort4*)h_hi,
                                             (const float4*)pw, pb, l + 1, out);
    }
    k_sigmoid<<<1, 288, 0, stream>>>(out);
}

// Round 6
// 420.908 us; speedup vs baseline: 3.2602x; 1.2379x over previous
//
#include <hip/hip_runtime.h>
#include <hip/hip_bf16.h>

#define NN 2048
#define QQ 9
#define DD 256
#define LL 4
#define BB 32
#define EE 32768
#define EPSV 1e-5f

typedef __attribute__((ext_vector_type(8))) short bf16x8;
typedef __attribute__((ext_vector_type(8))) ushort u16x8;
typedef __attribute__((ext_vector_type(4))) float f32x4;
typedef __attribute__((ext_vector_type(4))) int i32x4;

__device__ __forceinline__ ushort f2bf(float x)
{
    uint u = __float_as_uint(x);
    u += 0x7FFFu + ((u >> 16) & 1u);
    return (ushort)(u >> 16);
}
__device__ __forceinline__ float bf2f(ushort h)
{
    return __uint_as_float(((uint)h) << 16);
}

// ---------- CSR build ----------
__global__ void k_count(const int* __restrict__ src, int* __restrict__ cnt)
{
    int e = blockIdx.x * blockDim.x + threadIdx.x;
    if (e < EE) atomicAdd(&cnt[src[e]], 1);
}

__global__ __launch_bounds__(256) void k_scan(const int* __restrict__ cnt,
                                              int* __restrict__ row_ptr,
                                              int* __restrict__ cursor)
{
    __shared__ int part[256];
    int t = threadIdx.x;
    int local[8];
    int s = 0;
    #pragma unroll
    for (int i = 0; i < 8; ++i) { local[i] = cnt[t * 8 + i]; s += local[i]; }
    part[t] = s;
    __syncthreads();
    for (int off = 1; off < 256; off <<= 1) {
        int v = (t >= off) ? part[t - off] : 0;
        __syncthreads();
        part[t] += v;
        __syncthreads();
    }
    int run = part[t] - s;
    #pragma unroll
    for (int i = 0; i < 8; ++i) {
        int idx = t * 8 + i;
        row_ptr[idx] = run;
        cursor[idx]  = run;
        run += local[i];
    }
    if (t == 255) row_ptr[NN] = run;
}

__global__ void k_fill(const int* __restrict__ src, const int* __restrict__ dst,
                       int* __restrict__ cursor, int* __restrict__ col)
{
    int e = blockIdx.x * blockDim.x + threadIdx.x;
    if (e < EE) {
        int p = atomicAdd(&cursor[src[e]], 1);
        col[p] = dst[e];
    }
}

// ---------- h0 = bf16(batch with rows [0,Q) <- emotion_emb) ----------
__global__ void k_prep0(const float4* __restrict__ bf, const float4* __restrict__ emo,
                        ushort4* __restrict__ hhi)
{
    int total = BB * NN * (DD / 4);
    for (int idx = blockIdx.x * blockDim.x + threadIdx.x; idx < total;
         idx += gridDim.x * blockDim.x) {
        int d4 = idx & 63;
        int n  = (idx >> 6) & (NN - 1);
        float4 v = (n < QQ) ? emo[n * 64 + d4] : bf[idx];
        ushort4 h;
        h.x = f2bf(v.x); h.y = f2bf(v.y); h.z = f2bf(v.z); h.w = f2bf(v.w);
        hhi[idx] = h;
    }
}

// ---------- pooled = h + A.h : bf16 gather, f32 accumulate, bf16 out ----------
__global__ __launch_bounds__(256) void k_spmm5(
    const ushort* __restrict__ phi,
    const int* __restrict__ row_ptr, const int* __restrict__ col,
    ushort* __restrict__ ohi)
{
    int x  = blockIdx.x & 7;             // XCD slice: batches [4x, 4x+4)
    int rb = blockIdx.x >> 3;
    int w  = threadIdx.x >> 6;
    int t  = threadIdx.x & 63;           // lane owns elements [4t, 4t+4)
    int row = x * 8192 + rb * 4 + w;     // = b*NN + n
    int n = row & (NN - 1);
    const ushort4* hb = (const ushort4*)(phi + (size_t)(row - n) * DD);

    ushort4 sv = hb[(size_t)n * 64 + t];
    float a0 = bf2f(sv.x), a1 = bf2f(sv.y), a2 = bf2f(sv.z), a3 = bf2f(sv.w);

    int beg = row_ptr[n], end = row_ptr[n + 1];
    int j = beg;
    for (; j < end && (j & 3); ++j) {
        ushort4 g = hb[(size_t)col[j] * 64 + t];
        a0 += bf2f(g.x); a1 += bf2f(g.y); a2 += bf2f(g.z); a3 += bf2f(g.w);
    }
    for (; j + 8 <= end; j += 8) {
        i32x4 c0 = *(const i32x4*)(col + j);
        i32x4 c1 = *(const i32x4*)(col + j + 4);
        ushort4 g[8];
        g[0] = hb[(size_t)c0.x * 64 + t];
        g[1] = hb[(size_t)c0.y * 64 + t];
        g[2] = hb[(size_t)c0.z * 64 + t];
        g[3] = hb[(size_t)c0.w * 64 + t];
        g[4] = hb[(size_t)c1.x * 64 + t];
        g[5] = hb[(size_t)c1.y * 64 + t];
        g[6] = hb[(size_t)c1.z * 64 + t];
        g[7] = hb[(size_t)c1.w * 64 + t];
        #pragma unroll
        for (int u = 0; u < 8; ++u) {
            a0 += bf2f(g[u].x); a1 += bf2f(g[u].y);
            a2 += bf2f(g[u].z); a3 += bf2f(g[u].w);
        }
    }
    if (j + 4 <= end) {
        i32x4 c = *(const i32x4*)(col + j);
        ushort4 g[4];
        g[0] = hb[(size_t)c.x * 64 + t];
        g[1] = hb[(size_t)c.y * 64 + t];
        g[2] = hb[(size_t)c.z * 64 + t];
        g[3] = hb[(size_t)c.w * 64 + t];
        #pragma unroll
        for (int u = 0; u < 4; ++u) {
            a0 += bf2f(g[u].x); a1 += bf2f(g[u].y);
            a2 += bf2f(g[u].z); a3 += bf2f(g[u].w);
        }
        j += 4;
    }
    for (; j < end; ++j) {
        ushort4 g = hb[(size_t)col[j] * 64 + t];
        a0 += bf2f(g.x); a1 += bf2f(g.y); a2 += bf2f(g.z); a3 += bf2f(g.w);
    }

    ushort4 oh;
    oh.x = f2bf(a0); oh.y = f2bf(a1); oh.z = f2bf(a2); oh.w = f2bf(a3);
    ((ushort4*)(ohi + (size_t)row * DD))[t] = oh;
}

// ---------- weight prep: Wt[mat][n][k] = bf16(W[mat][k][n]) ----------
__global__ __launch_bounds__(256) void k_wprep(const float* __restrict__ w1,
                                               const float* __restrict__ w2,
                                               ushort* __restrict__ wt_hi)
{
    __shared__ float tile[32][36];
    int bx = blockIdx.x;
    int mat = bx >> 6;
    int tt  = bx & 63;
    int tk = (tt >> 3) * 32;
    int tn = (tt & 7) * 32;
    const float* src = (mat < 4) ? (w1 + (size_t)mat * DD * DD)
                                 : (w2 + (size_t)(mat - 4) * DD * DD);
    int t = threadIdx.x;
    int r = t >> 3, c0 = (t & 7) * 4;
    float4 v = *(const float4*)(src + (size_t)(tk + r) * DD + tn + c0);
    tile[r][c0 + 0] = v.x; tile[r][c0 + 1] = v.y;
    tile[r][c0 + 2] = v.z; tile[r][c0 + 3] = v.w;
    __syncthreads();
    int nn = t >> 3, kq = (t & 7) * 4;
    ushort4 hh;
    hh.x = f2bf(tile[kq + 0][nn]); hh.y = f2bf(tile[kq + 1][nn]);
    hh.z = f2bf(tile[kq + 2][nn]); hh.w = f2bf(tile[kq + 3][nn]);
    size_t off = (size_t)mat * DD * DD + (size_t)(tn + nn) * DD + tk + kq;
    *(ushort4*)(wt_hi + off) = hh;
}

// ---------- plain-bf16 MFMA GEMM: O = bf16(relu(bn(A @ W + bias))) ----------
__global__ __launch_bounds__(256) void k_gemm5(
    const ushort* __restrict__ Ahi, const ushort* __restrict__ Whi,
    const float* __restrict__ bias, const float* __restrict__ gg,
    const float* __restrict__ bb, const float* __restrict__ mm,
    const float* __restrict__ vv,
    ushort* __restrict__ Ohi)
{
    __shared__ alignas(16) ushort SM[2 * 5120];          // A,W planes 128x40
    ushort (*As)[40] = (ushort(*)[40])(SM);
    ushort (*Ws)[40] = (ushort(*)[40])(SM + 5120);

    int tid = threadIdx.x;
    int bm0 = (int)(blockIdx.x >> 1) * 128;
    int bn0 = (int)(blockIdx.x & 1) * 128;
    int lane = tid & 63;
    int w = tid >> 6;
    int wm = w & 1, wn = w >> 1;
    int lr = lane & 15, kg = lane >> 4;

    f32x4 acc[4][4];
    #pragma unroll
    for (int m = 0; m < 4; ++m)
        #pragma unroll
        for (int n = 0; n < 4; ++n) acc[m][n] = (f32x4)0.f;

    for (int kc = 0; kc < 8; ++kc) {
        int k0 = kc * 32;
        __syncthreads();
        #pragma unroll
        for (int i = 0; i < 2; ++i) {
            int idx = tid + i * 256;
            int r = idx >> 2, k8 = (idx & 3) * 8;
            *(float4*)&As[r][k8] = *(const float4*)(Ahi + (size_t)(bm0 + r) * DD + k0 + k8);
            *(float4*)&Ws[r][k8] = *(const float4*)(Whi + (size_t)(bn0 + r) * DD + k0 + k8);
        }
        __syncthreads();
        bf16x8 ah[4], bh[4];
        #pragma unroll
        for (int m = 0; m < 4; ++m)
            ah[m] = *(const bf16x8*)&As[wm * 64 + m * 16 + lr][kg * 8];
        #pragma unroll
        for (int n = 0; n < 4; ++n)
            bh[n] = *(const bf16x8*)&Ws[wn * 64 + n * 16 + lr][kg * 8];
        #pragma unroll
        for (int m = 0; m < 4; ++m)
            #pragma unroll
            for (int n = 0; n < 4; ++n)
                acc[m][n] = __builtin_amdgcn_mfma_f32_16x16x32_bf16(ah[m], bh[n], acc[m][n], 0, 0, 0);
    }

    // ---- epilogue: BN+ReLU, repack via per-wave LDS scratch, 16B stores ----
    __syncthreads();
    float* ep = (float*)SM + (size_t)w * (16 * 68) % (2 * 5120 / 2);  // see below
    // NOTE: 4 waves x 16x68 f32 = 17408 B < 20480 B LDS; lay out contiguously:
    ep = (float*)SM + (size_t)w * (16 * 68);
    float sN[4], svN[4];
    #pragma unroll
    for (int n = 0; n < 4; ++n) {
        int jj = bn0 + wn * 64 + n * 16 + lr;
        sN[n]  = gg[jj] * rsqrtf(vv[jj] + EPSV);
        svN[n] = (bias[jj] - mm[jj]) * sN[n] + bb[jj];
    }
    int rg = lane >> 4;
    int rl = lane >> 2;
    int cb = (lane & 3) * 16;
    #pragma unroll
    for (int m = 0; m < 4; ++m) {
        __syncthreads();
        #pragma unroll
        for (int n = 0; n < 4; ++n) {
            int cc = n * 16 + lr;
            #pragma unroll
            for (int r = 0; r < 4; ++r) {
                float y = acc[m][n][r] * sN[n] + svN[n];
                ep[(rg * 4 + r) * 68 + cc] = y > 0.f ? y : 0.f;
            }
        }
        f32x4 v0 = *(const f32x4*)&ep[rl * 68 + cb + 0];
        f32x4 v1 = *(const f32x4*)&ep[rl * 68 + cb + 4];
        f32x4 v2 = *(const f32x4*)&ep[rl * 68 + cb + 8];
        f32x4 v3 = *(const f32x4*)&ep[rl * 68 + cb + 12];
        u16x8 hh0, hh1;
        #pragma unroll
        for (int c = 0; c < 4; ++c) {
            hh0[c]     = f2bf(v0[c]);
            hh0[4 + c] = f2bf(v1[c]);
            hh1[c]     = f2bf(v2[c]);
            hh1[4 + c] = f2bf(v3[c]);
        }
        size_t o = (size_t)(bm0 + wm * 64 + m * 16 + rl) * DD + bn0 + wn * 64 + cb;
        *(u16x8*)(Ohi + o) = hh0;
        *(u16x8*)(Ohi + o + 8) = hh1;
    }
}

// ---------- layer-0 score: batch-independent; ASSIGNS output ----------
__global__ __launch_bounds__(64) void k_score0(const float4* __restrict__ emo,
                                               const float4* __restrict__ pw,
                                               const float* __restrict__ pb,
                                               float* __restrict__ out)
{
    int q = blockIdx.x, t = threadIdx.x;
    float4 e = emo[q * 64 + t], wv = pw[t];
    float s = e.x * wv.x + e.y * wv.y + e.z * wv.z + e.w * wv.w;
    #pragma unroll
    for (int off = 32; off > 0; off >>= 1) s += __shfl_down(s, off);
    if (t == 0) {
        s += pb[0];
        for (int b = 0; b < BB; ++b) out[b * QQ + q] = s;
    }
}

// ---------- score layers 1..4 ----------
__global__ __launch_bounds__(64) void k_score2(const ushort4* __restrict__ hhi,
                                               const float4* __restrict__ pw,
                                               const float* __restrict__ pb, int l,
                                               float* __restrict__ out)
{
    int bid = blockIdx.x;
    int b = bid / QQ, q = bid % QQ;
    int t = threadIdx.x;
    size_t o = ((size_t)b * NN + q) * 64 + t;
    ushort4 hh = hhi[o];
    float4 wv = pw[l * 64 + t];
    float sum = bf2f(hh.x) * wv.x + bf2f(hh.y) * wv.y +
                bf2f(hh.z) * wv.z + bf2f(hh.w) * wv.w;
    #pragma unroll
    for (int off = 32; off > 0; off >>= 1) sum += __shfl_down(sum, off);
    if (t == 0) out[bid] += sum + pb[l];
}

__global__ void k_sigmoid(float* out)
{
    int i = threadIdx.x + blockIdx.x * blockDim.x;
    if (i < BB * QQ) out[i] = 1.f / (1.f + expf(-out[i]));
}

extern "C" void kernel_launch(void* const* d_in, const int* in_sizes, int n_in,
                              void* d_out, int out_size, void* d_ws, size_t ws_size,
                              hipStream_t stream)
{
    const float* batch = (const float*)d_in[0];
    const int*   edges = (const int*)d_in[1];
    const float* emo   = (const float*)d_in[2];
    const float* w1    = (const float*)d_in[3];
    const float* b1    = (const float*)d_in[4];
    const float* m_g   = (const float*)d_in[5];
    const float* m_b   = (const float*)d_in[6];
    const float* m_m   = (const float*)d_in[7];
    const float* m_v   = (const float*)d_in[8];
    const float* w2    = (const float*)d_in[9];
    const float* b2    = (const float*)d_in[10];
    const float* g_g   = (const float*)d_in[11];
    const float* g_b   = (const float*)d_in[12];
    const float* g_m   = (const float*)d_in[13];
    const float* g_v   = (const float*)d_in[14];
    const float* pw    = (const float*)d_in[15];
    const float* pb    = (const float*)d_in[16];
    float* out = (float*)d_out;

    const size_t HSZ = (size_t)BB * NN * DD;
    const size_t WT  = (size_t)8 * DD * DD;

    ushort* h_hi = (ushort*)d_ws;
    ushort* P_hi = h_hi + HSZ;
    ushort* T_hi = P_hi + HSZ;
    ushort* wt_hi = T_hi + HSZ;
    int* cnt     = (int*)(wt_hi + WT);
    int* row_ptr = cnt + NN;
    int* cursor  = row_ptr + (NN + 4);
    int* col     = cursor + NN;            // 16B-aligned

    const int* src = edges;
    const int* dst = edges + EE;

    hipMemsetAsync(cnt, 0, NN * sizeof(int), stream);
    k_count<<<EE / 256, 256, 0, stream>>>(src, cnt);
    k_scan<<<1, 256, 0, stream>>>(cnt, row_ptr, cursor);
    k_fill<<<EE / 256, 256, 0, stream>>>(src, dst, cursor, col);
    k_wprep<<<512, 256, 0, stream>>>(w1, w2, wt_hi);
    k_prep0<<<4096, 256, 0, stream>>>((const float4*)batch, (const float4*)emo,
                                      (ushort4*)h_hi);
    k_score0<<<QQ, 64, 0, stream>>>((const float4*)emo, (const float4*)pw, pb, out);

    for (int l = 0; l < LL; ++l) {
        k_spmm5<<<16384, 256, 0, stream>>>(h_hi, row_ptr, col, P_hi);
        k_gemm5<<<1024, 256, 0, stream>>>(
            P_hi, wt_hi + (size_t)l * DD * DD,
            b1 + l * DD, m_g + l * DD, m_b + l * DD, m_m + l * DD, m_v + l * DD,
            T_hi);
        k_gemm5<<<1024, 256, 0, stream>>>(
            T_hi, wt_hi + (size_t)(4 + l) * DD * DD,
            b2 + l * DD, g_g + l * DD, g_b + l * DD, g_m + l * DD, g_v + l * DD,
            h_hi);
        k_score2<<<BB * QQ, 64, 0, stream>>>((const ushort4*)h_hi,
                                             (const float4*)pw, pb, l + 1, out);
    }
    k_sigmoid<<<1, 288, 0, stream>>>(out);
}

// Round 7
// 386.230 us; speedup vs baseline: 3.5529x; 1.0898x over previous
//
#include <hip/hip_runtime.h>
#include <hip/hip_bf16.h>

#define NN 2048
#define QQ 9
#define DD 256
#define LL 4
#define BB 32
#define EE 32768
#define EPSV 1e-5f

typedef __attribute__((ext_vector_type(8))) short bf16x8;
typedef __attribute__((ext_vector_type(8))) ushort u16x8;
typedef __attribute__((ext_vector_type(4))) float f32x4;
typedef __attribute__((ext_vector_type(4))) int i32x4;

__device__ __forceinline__ ushort f2bf(float x)
{
    uint u = __float_as_uint(x);
    u += 0x7FFFu + ((u >> 16) & 1u);
    return (ushort)(u >> 16);
}
__device__ __forceinline__ float bf2f(ushort h)
{
    return __uint_as_float(((uint)h) << 16);
}

// ---------- CSR build ----------
__global__ void k_count(const int* __restrict__ src, int* __restrict__ cnt)
{
    int e = blockIdx.x * blockDim.x + threadIdx.x;
    if (e < EE) atomicAdd(&cnt[src[e]], 1);
}

__global__ __launch_bounds__(256) void k_scan(const int* __restrict__ cnt,
                                              int* __restrict__ row_ptr,
                                              int* __restrict__ cursor)
{
    __shared__ int part[256];
    int t = threadIdx.x;
    int local[8];
    int s = 0;
    #pragma unroll
    for (int i = 0; i < 8; ++i) { local[i] = cnt[t * 8 + i]; s += local[i]; }
    part[t] = s;
    __syncthreads();
    for (int off = 1; off < 256; off <<= 1) {
        int v = (t >= off) ? part[t - off] : 0;
        __syncthreads();
        part[t] += v;
        __syncthreads();
    }
    int run = part[t] - s;
    #pragma unroll
    for (int i = 0; i < 8; ++i) {
        int idx = t * 8 + i;
        row_ptr[idx] = run;
        cursor[idx]  = run;
        run += local[i];
    }
    if (t == 255) row_ptr[NN] = run;
}

__global__ void k_fill(const int* __restrict__ src, const int* __restrict__ dst,
                       int* __restrict__ cursor, int* __restrict__ col)
{
    int e = blockIdx.x * blockDim.x + threadIdx.x;
    if (e < EE) {
        int p = atomicAdd(&cursor[src[e]], 1);
        col[p] = dst[e];
    }
}

// ---------- h0 = bf16(batch with rows [0,Q) <- emotion_emb) ----------
__global__ void k_prep0(const float4* __restrict__ bf, const float4* __restrict__ emo,
                        ushort4* __restrict__ hhi)
{
    int total = BB * NN * (DD / 4);
    for (int idx = blockIdx.x * blockDim.x + threadIdx.x; idx < total;
         idx += gridDim.x * blockDim.x) {
        int d4 = idx & 63;
        int n  = (idx >> 6) & (NN - 1);
        float4 v = (n < QQ) ? emo[n * 64 + d4] : bf[idx];
        ushort4 h;
        h.x = f2bf(v.x); h.y = f2bf(v.y); h.z = f2bf(v.z); h.w = f2bf(v.w);
        hhi[idx] = h;
    }
}

// ---------- pooled = h + A.h : batch-paired gather (2 batches per wave) ----------
__global__ __launch_bounds__(256) void k_spmm6(
    const ushort* __restrict__ phi,
    const int* __restrict__ row_ptr, const int* __restrict__ col,
    ushort* __restrict__ ohi)
{
    int x     = blockIdx.x & 7;          // XCD slice: batches [4x, 4x+4)
    int local = blockIdx.x >> 3;
    int w     = threadIdx.x >> 6;
    int t     = threadIdx.x & 63;
    int inst  = local * 4 + w;           // [0, 4096): (pair-of-batches, node)
    int pl    = inst >> 11;              // 0/1: which batch pair in this XCD
    int n     = inst & (NN - 1);
    int b     = x * 4 + pl * 2 + (t >> 5);   // lanes 0-31: batch b0; 32-63: b0+1
    int q     = t & 31;                  // 16B chunk: elems [8q, 8q+8)
    const ushort* base = phi + (size_t)b * NN * DD + q * 8;

    u16x8 sv = *(const u16x8*)(base + (size_t)n * DD);
    float a[8];
    #pragma unroll
    for (int k = 0; k < 8; ++k) a[k] = bf2f((ushort)sv[k]);

    int beg = row_ptr[n], end = row_ptr[n + 1];
    int j = beg;
    for (; j < end && (j & 3); ++j) {
        u16x8 g = *(const u16x8*)(base + (size_t)col[j] * DD);
        #pragma unroll
        for (int k = 0; k < 8; ++k) a[k] += bf2f((ushort)g[k]);
    }
    for (; j + 8 <= end; j += 8) {
        i32x4 c0 = *(const i32x4*)(col + j);
        i32x4 c1 = *(const i32x4*)(col + j + 4);
        u16x8 g[8];
        g[0] = *(const u16x8*)(base + (size_t)c0.x * DD);
        g[1] = *(const u16x8*)(base + (size_t)c0.y * DD);
        g[2] = *(const u16x8*)(base + (size_t)c0.z * DD);
        g[3] = *(const u16x8*)(base + (size_t)c0.w * DD);
        g[4] = *(const u16x8*)(base + (size_t)c1.x * DD);
        g[5] = *(const u16x8*)(base + (size_t)c1.y * DD);
        g[6] = *(const u16x8*)(base + (size_t)c1.z * DD);
        g[7] = *(const u16x8*)(base + (size_t)c1.w * DD);
        #pragma unroll
        for (int u = 0; u < 8; ++u)
            #pragma unroll
            for (int k = 0; k < 8; ++k) a[k] += bf2f((ushort)g[u][k]);
    }
    if (j + 4 <= end) {
        i32x4 c = *(const i32x4*)(col + j);
        u16x8 g[4];
        g[0] = *(const u16x8*)(base + (size_t)c.x * DD);
        g[1] = *(const u16x8*)(base + (size_t)c.y * DD);
        g[2] = *(const u16x8*)(base + (size_t)c.z * DD);
        g[3] = *(const u16x8*)(base + (size_t)c.w * DD);
        #pragma unroll
        for (int u = 0; u < 4; ++u)
            #pragma unroll
            for (int k = 0; k < 8; ++k) a[k] += bf2f((ushort)g[u][k]);
        j += 4;
    }
    for (; j < end; ++j) {
        u16x8 g = *(const u16x8*)(base + (size_t)col[j] * DD);
        #pragma unroll
        for (int k = 0; k < 8; ++k) a[k] += bf2f((ushort)g[k]);
    }

    u16x8 o;
    #pragma unroll
    for (int k = 0; k < 8; ++k) o[k] = f2bf(a[k]);
    *(u16x8*)(ohi + ((size_t)b * NN + n) * DD + q * 8) = o;
}

// ---------- weight prep: Wt[mat][n][k] = bf16(W[mat][k][n]) ----------
__global__ __launch_bounds__(256) void k_wprep(const float* __restrict__ w1,
                                               const float* __restrict__ w2,
                                               ushort* __restrict__ wt_hi)
{
    __shared__ float tile[32][36];
    int bx = blockIdx.x;
    int mat = bx >> 6;
    int tt  = bx & 63;
    int tk = (tt >> 3) * 32;
    int tn = (tt & 7) * 32;
    const float* src = (mat < 4) ? (w1 + (size_t)mat * DD * DD)
                                 : (w2 + (size_t)(mat - 4) * DD * DD);
    int t = threadIdx.x;
    int r = t >> 3, c0 = (t & 7) * 4;
    float4 v = *(const float4*)(src + (size_t)(tk + r) * DD + tn + c0);
    tile[r][c0 + 0] = v.x; tile[r][c0 + 1] = v.y;
    tile[r][c0 + 2] = v.z; tile[r][c0 + 3] = v.w;
    __syncthreads();
    int nn = t >> 3, kq = (t & 7) * 4;
    ushort4 hh;
    hh.x = f2bf(tile[kq + 0][nn]); hh.y = f2bf(tile[kq + 1][nn]);
    hh.z = f2bf(tile[kq + 2][nn]); hh.w = f2bf(tile[kq + 3][nn]);
    size_t off = (size_t)mat * DD * DD + (size_t)(tn + nn) * DD + tk + kq;
    *(ushort4*)(wt_hi + off) = hh;
}

// ---------- full-N MFMA GEMM: 128x256 tile, O = bf16(relu(bn(A @ W + bias))) ----------
__global__ __launch_bounds__(256, 2) void k_gemm6(
    const ushort* __restrict__ Ahi, const ushort* __restrict__ Whi,
    const float* __restrict__ bias, const float* __restrict__ gg,
    const float* __restrict__ bb, const float* __restrict__ mm,
    const float* __restrict__ vv,
    ushort* __restrict__ Ohi)
{
    __shared__ alignas(16) ushort SM[16896];             // 33,792 B
    ushort (*As)[40] = (ushort(*)[40])(SM);              // [128][40]
    ushort (*Ws)[40] = (ushort(*)[40])(SM + 5120);       // [256][40]

    int tid = threadIdx.x;
    int x  = blockIdx.x & 7;                 // XCD-aligned with spmm partition
    int lm = blockIdx.x >> 3;
    int m0 = x * 8192 + lm * 128;
    int lane = tid & 63;
    int w = tid >> 6;
    int wm = w & 1, wn = w >> 1;             // wave tile: 64m x 128n
    int lr = lane & 15, kg = lane >> 4;

    f32x4 acc[4][8];
    #pragma unroll
    for (int m = 0; m < 4; ++m)
        #pragma unroll
        for (int n = 0; n < 8; ++n) acc[m][n] = (f32x4)0.f;

    for (int kc = 0; kc < 8; ++kc) {
        int k0 = kc * 32;
        __syncthreads();
        #pragma unroll
        for (int i = 0; i < 2; ++i) {        // A tile: 128 rows x 32 k
            int idx = tid + i * 256;
            int r = idx >> 2, k8 = (idx & 3) * 8;
            *(float4*)&As[r][k8] = *(const float4*)(Ahi + (size_t)(m0 + r) * DD + k0 + k8);
        }
        #pragma unroll
        for (int i = 0; i < 4; ++i) {        // W^T tile: 256 n x 32 k
            int idx = tid + i * 256;
            int r = idx >> 2, k8 = (idx & 3) * 8;
            *(float4*)&Ws[r][k8] = *(const float4*)(Whi + (size_t)r * DD + k0 + k8);
        }
        __syncthreads();
        bf16x8 ah[4], bh[8];
        #pragma unroll
        for (int m = 0; m < 4; ++m)
            ah[m] = *(const bf16x8*)&As[wm * 64 + m * 16 + lr][kg * 8];
        #pragma unroll
        for (int n = 0; n < 8; ++n)
            bh[n] = *(const bf16x8*)&Ws[wn * 128 + n * 16 + lr][kg * 8];
        #pragma unroll
        for (int m = 0; m < 4; ++m)
            #pragma unroll
            for (int n = 0; n < 8; ++n)
                acc[m][n] = __builtin_amdgcn_mfma_f32_16x16x32_bf16(ah[m], bh[n], acc[m][n], 0, 0, 0);
    }

    // ---- epilogue: BN+ReLU, per-wave LDS repack, 16B coalesced stores ----
    __syncthreads();
    float* ep = (float*)SM + (size_t)w * (16 * 132);     // [16][132] f32 per wave
    float sN[8], svN[8];
    #pragma unroll
    for (int n = 0; n < 8; ++n) {
        int jj = wn * 128 + n * 16 + lr;
        sN[n]  = gg[jj] * rsqrtf(vv[jj] + EPSV);
        svN[n] = (bias[jj] - mm[jj]) * sN[n] + bb[jj];
    }
    int rg = lane >> 4;
    int rl = lane >> 2;              // read row 0..15
    int cb = (lane & 3) * 32;        // read col base 0/32/64/96
    #pragma unroll
    for (int m = 0; m < 4; ++m) {
        #pragma unroll
        for (int n = 0; n < 8; ++n) {
            int cc = n * 16 + lr;
            #pragma unroll
            for (int r = 0; r < 4; ++r) {
                float y = acc[m][n][r] * sN[n] + svN[n];
                ep[(rg * 4 + r) * 132 + cc] = y > 0.f ? y : 0.f;
            }
        }
        size_t o = (size_t)(m0 + wm * 64 + m * 16 + rl) * DD + wn * 128 + cb;
        #pragma unroll
        for (int h = 0; h < 2; ++h) {
            f32x4 v0 = *(const f32x4*)&ep[rl * 132 + cb + h * 16 + 0];
            f32x4 v1 = *(const f32x4*)&ep[rl * 132 + cb + h * 16 + 4];
            f32x4 v2 = *(const f32x4*)&ep[rl * 132 + cb + h * 16 + 8];
            f32x4 v3 = *(const f32x4*)&ep[rl * 132 + cb + h * 16 + 12];
            u16x8 hh0, hh1;
            #pragma unroll
            for (int c = 0; c < 4; ++c) {
                hh0[c]     = f2bf(v0[c]);
                hh0[4 + c] = f2bf(v1[c]);
                hh1[c]     = f2bf(v2[c]);
                hh1[4 + c] = f2bf(v3[c]);
            }
            *(u16x8*)(Ohi + o + h * 16)     = hh0;
            *(u16x8*)(Ohi + o + h * 16 + 8) = hh1;
        }
    }
}

// ---------- layer-0 score: batch-independent; ASSIGNS output ----------
__global__ __launch_bounds__(64) void k_score0(const float4* __restrict__ emo,
                                               const float4* __restrict__ pw,
                                               const float* __restrict__ pb,
                                               float* __restrict__ out)
{
    int q = blockIdx.x, t = threadIdx.x;
    float4 e = emo[q * 64 + t], wv = pw[t];
    float s = e.x * wv.x + e.y * wv.y + e.z * wv.z + e.w * wv.w;
    #pragma unroll
    for (int off = 32; off > 0; off >>= 1) s += __shfl_down(s, off);
    if (t == 0) {
        s += pb[0];
        for (int b = 0; b < BB; ++b) out[b * QQ + q] = s;
    }
}

// ---------- score layers 1..4 ----------
__global__ __launch_bounds__(64) void k_score2(const ushort4* __restrict__ hhi,
                                               const float4* __restrict__ pw,
                                               const float* __restrict__ pb, int l,
                                               float* __restrict__ out)
{
    int bid = blockIdx.x;
    int b = bid / QQ, q = bid % QQ;
    int t = threadIdx.x;
    size_t o = ((size_t)b * NN + q) * 64 + t;
    ushort4 hh = hhi[o];
    float4 wv = pw[l * 64 + t];
    float sum = bf2f(hh.x) * wv.x + bf2f(hh.y) * wv.y +
                bf2f(hh.z) * wv.z + bf2f(hh.w) * wv.w;
    #pragma unroll
    for (int off = 32; off > 0; off >>= 1) sum += __shfl_down(sum, off);
    if (t == 0) out[bid] += sum + pb[l];
}

__global__ void k_sigmoid(float* out)
{
    int i = threadIdx.x + blockIdx.x * blockDim.x;
    if (i < BB * QQ) out[i] = 1.f / (1.f + expf(-out[i]));
}

extern "C" void kernel_launch(void* const* d_in, const int* in_sizes, int n_in,
                              void* d_out, int out_size, void* d_ws, size_t ws_size,
                              hipStream_t stream)
{
    const float* batch = (const float*)d_in[0];
    const int*   edges = (const int*)d_in[1];
    const float* emo   = (const float*)d_in[2];
    const float* w1    = (const float*)d_in[3];
    const float* b1    = (const float*)d_in[4];
    const float* m_g   = (const float*)d_in[5];
    const float* m_b   = (const float*)d_in[6];
    const float* m_m   = (const float*)d_in[7];
    const float* m_v   = (const float*)d_in[8];
    const float* w2    = (const float*)d_in[9];
    const float* b2    = (const float*)d_in[10];
    const float* g_g   = (const float*)d_in[11];
    const float* g_b   = (const float*)d_in[12];
    const float* g_m   = (const float*)d_in[13];
    const float* g_v   = (const float*)d_in[14];
    const float* pw    = (const float*)d_in[15];
    const float* pb    = (const float*)d_in[16];
    float* out = (float*)d_out;

    const size_t HSZ = (size_t)BB * NN * DD;
    const size_t WT  = (size_t)8 * DD * DD;

    ushort* h_hi = (ushort*)d_ws;
    ushort* P_hi = h_hi + HSZ;
    ushort* T_hi = P_hi + HSZ;
    ushort* wt_hi = T_hi + HSZ;
    int* cnt     = (int*)(wt_hi + WT);
    int* row_ptr = cnt + NN;
    int* cursor  = row_ptr + (NN + 4);
    int* col     = cursor + NN;            // 16B-aligned

    const int* src = edges;
    const int* dst = edges + EE;

    hipMemsetAsync(cnt, 0, NN * sizeof(int), stream);
    k_count<<<EE / 256, 256, 0, stream>>>(src, cnt);
    k_scan<<<1, 256, 0, stream>>>(cnt, row_ptr, cursor);
    k_fill<<<EE / 256, 256, 0, stream>>>(src, dst, cursor, col);
    k_wprep<<<512, 256, 0, stream>>>(w1, w2, wt_hi);
    k_prep0<<<4096, 256, 0, stream>>>((const float4*)batch, (const float4*)emo,
                                      (ushort4*)h_hi);
    k_score0<<<QQ, 64, 0, stream>>>((const float4*)emo, (const float4*)pw, pb, out);

    for (int l = 0; l < LL; ++l) {
        k_spmm6<<<8192, 256, 0, stream>>>(h_hi, row_ptr, col, P_hi);
        k_gemm6<<<512, 256, 0, stream>>>(
            P_hi, wt_hi + (size_t)l * DD * DD,
            b1 + l * DD, m_g + l * DD, m_b + l * DD, m_m + l * DD, m_v + l * DD,
            T_hi);
        k_gemm6<<<512, 256, 0, stream>>>(
            T_hi, wt_hi + (size_t)(4 + l) * DD * DD,
            b2 + l * DD, g_g + l * DD, g_b + l * DD, g_m + l * DD, g_v + l * DD,
            h_hi);
        k_score2<<<BB * QQ, 64, 0, stream>>>((const ushort4*)h_hi,
                                             (const float4*)pw, pb, l + 1, out);
    }
    k_sigmoid<<<1, 288, 0, stream>>>(out);
}

// Round 9
// 334.504 us; speedup vs baseline: 4.1024x; 1.1546x over previous
//
#include <hip/hip_runtime.h>
#include <hip/hip_bf16.h>

#define NN 2048
#define QQ 9
#define DD 256
#define LL 4
#define BB 32
#define EE 32768
#define EPSV 1e-5f

typedef __attribute__((ext_vector_type(8))) short bf16x8;
typedef __attribute__((ext_vector_type(8))) ushort u16x8;
typedef __attribute__((ext_vector_type(4))) float f32x4;
typedef __attribute__((ext_vector_type(4))) int i32x4;

__device__ __forceinline__ ushort f2bf(float x)
{
    uint u = __float_as_uint(x);
    u += 0x7FFFu + ((u >> 16) & 1u);
    return (ushort)(u >> 16);
}
__device__ __forceinline__ float bf2f(ushort h)
{
    return __uint_as_float(((uint)h) << 16);
}

// ---------- CSR build ----------
__global__ void k_count(const int* __restrict__ src, int* __restrict__ cnt)
{
    int e = blockIdx.x * blockDim.x + threadIdx.x;
    if (e < EE) atomicAdd(&cnt[src[e]], 1);
}

__global__ __launch_bounds__(256) void k_scan(const int* __restrict__ cnt,
                                              int* __restrict__ row_ptr,
                                              int* __restrict__ cursor)
{
    __shared__ int part[256];
    int t = threadIdx.x;
    int local[8];
    int s = 0;
    #pragma unroll
    for (int i = 0; i < 8; ++i) { local[i] = cnt[t * 8 + i]; s += local[i]; }
    part[t] = s;
    __syncthreads();
    for (int off = 1; off < 256; off <<= 1) {
        int v = (t >= off) ? part[t - off] : 0;
        __syncthreads();
        part[t] += v;
        __syncthreads();
    }
    int run = part[t] - s;
    #pragma unroll
    for (int i = 0; i < 8; ++i) {
        int idx = t * 8 + i;
        row_ptr[idx] = run;
        cursor[idx]  = run;
        run += local[i];
    }
    if (t == 255) row_ptr[NN] = run;
}

__global__ void k_fill(const int* __restrict__ src, const int* __restrict__ dst,
                       int* __restrict__ cursor, int* __restrict__ col)
{
    int e = blockIdx.x * blockDim.x + threadIdx.x;
    if (e < EE) {
        int p = atomicAdd(&cursor[src[e]], 1);
        col[p] = dst[e];
    }
}

// ---------- h0 = bf16(batch with rows [0,Q) <- emotion_emb) ----------
__global__ void k_prep0(const float4* __restrict__ bf, const float4* __restrict__ emo,
                        ushort4* __restrict__ hhi)
{
    int total = BB * NN * (DD / 4);
    for (int idx = blockIdx.x * blockDim.x + threadIdx.x; idx < total;
         idx += gridDim.x * blockDim.x) {
        int d4 = idx & 63;
        int n  = (idx >> 6) & (NN - 1);
        float4 v = (n < QQ) ? emo[n * 64 + d4] : bf[idx];
        ushort4 h;
        h.x = f2bf(v.x); h.y = f2bf(v.y); h.z = f2bf(v.z); h.w = f2bf(v.w);
        hhi[idx] = h;
    }
}

// ---------- pooled = h + A.h : batch-paired gather (2 batches per wave) ----------
__global__ __launch_bounds__(256) void k_spmm6(
    const ushort* __restrict__ phi,
    const int* __restrict__ row_ptr, const int* __restrict__ col,
    ushort* __restrict__ ohi)
{
    int x     = blockIdx.x & 7;          // XCD slice: batches [4x, 4x+4)
    int local = blockIdx.x >> 3;
    int w     = threadIdx.x >> 6;
    int t     = threadIdx.x & 63;
    int inst  = local * 4 + w;           // [0, 4096): (pair-of-batches, node)
    int pl    = inst >> 11;              // 0/1: which batch pair in this XCD
    int n     = inst & (NN - 1);
    int b     = x * 4 + pl * 2 + (t >> 5);   // lanes 0-31: batch b0; 32-63: b0+1
    int q     = t & 31;                  // 16B chunk: elems [8q, 8q+8)
    const ushort* base = phi + (size_t)b * NN * DD + q * 8;

    u16x8 sv = *(const u16x8*)(base + (size_t)n * DD);
    float a[8];
    #pragma unroll
    for (int k = 0; k < 8; ++k) a[k] = bf2f((ushort)sv[k]);

    int beg = row_ptr[n], end = row_ptr[n + 1];
    int j = beg;
    for (; j < end && (j & 3); ++j) {
        u16x8 g = *(const u16x8*)(base + (size_t)col[j] * DD);
        #pragma unroll
        for (int k = 0; k < 8; ++k) a[k] += bf2f((ushort)g[k]);
    }
    for (; j + 8 <= end; j += 8) {
        i32x4 c0 = *(const i32x4*)(col + j);
        i32x4 c1 = *(const i32x4*)(col + j + 4);
        u16x8 g[8];
        g[0] = *(const u16x8*)(base + (size_t)c0.x * DD);
        g[1] = *(const u16x8*)(base + (size_t)c0.y * DD);
        g[2] = *(const u16x8*)(base + (size_t)c0.z * DD);
        g[3] = *(const u16x8*)(base + (size_t)c0.w * DD);
        g[4] = *(const u16x8*)(base + (size_t)c1.x * DD);
        g[5] = *(const u16x8*)(base + (size_t)c1.y * DD);
        g[6] = *(const u16x8*)(base + (size_t)c1.z * DD);
        g[7] = *(const u16x8*)(base + (size_t)c1.w * DD);
        #pragma unroll
        for (int u = 0; u < 8; ++u)
            #pragma unroll
            for (int k = 0; k < 8; ++k) a[k] += bf2f((ushort)g[u][k]);
    }
    if (j + 4 <= end) {
        i32x4 c = *(const i32x4*)(col + j);
        u16x8 g[4];
        g[0] = *(const u16x8*)(base + (size_t)c.x * DD);
        g[1] = *(const u16x8*)(base + (size_t)c.y * DD);
        g[2] = *(const u16x8*)(base + (size_t)c.z * DD);
        g[3] = *(const u16x8*)(base + (size_t)c.w * DD);
        #pragma unroll
        for (int u = 0; u < 4; ++u)
            #pragma unroll
            for (int k = 0; k < 8; ++k) a[k] += bf2f((ushort)g[u][k]);
        j += 4;
    }
    for (; j < end; ++j) {
        u16x8 g = *(const u16x8*)(base + (size_t)col[j] * DD);
        #pragma unroll
        for (int k = 0; k < 8; ++k) a[k] += bf2f((ushort)g[k]);
    }

    u16x8 o;
    #pragma unroll
    for (int k = 0; k < 8; ++k) o[k] = f2bf(a[k]);
    *(u16x8*)(ohi + ((size_t)b * NN + n) * DD + q * 8) = o;
}

// ---------- weight prep: Wt[mat][n][k] = bf16(W[mat][k][n]) ----------
__global__ __launch_bounds__(256) void k_wprep(const float* __restrict__ w1,
                                               const float* __restrict__ w2,
                                               ushort* __restrict__ wt_hi)
{
    __shared__ float tile[32][36];
    int bx = blockIdx.x;
    int mat = bx >> 6;
    int tt  = bx & 63;
    int tk = (tt >> 3) * 32;
    int tn = (tt & 7) * 32;
    const float* src = (mat < 4) ? (w1 + (size_t)mat * DD * DD)
                                 : (w2 + (size_t)(mat - 4) * DD * DD);
    int t = threadIdx.x;
    int r = t >> 3, c0 = (t & 7) * 4;
    float4 v = *(const float4*)(src + (size_t)(tk + r) * DD + tn + c0);
    tile[r][c0 + 0] = v.x; tile[r][c0 + 1] = v.y;
    tile[r][c0 + 2] = v.z; tile[r][c0 + 3] = v.w;
    __syncthreads();
    int nn = t >> 3, kq = (t & 7) * 4;
    ushort4 hh;
    hh.x = f2bf(tile[kq + 0][nn]); hh.y = f2bf(tile[kq + 1][nn]);
    hh.z = f2bf(tile[kq + 2][nn]); hh.w = f2bf(tile[kq + 3][nn]);
    size_t off = (size_t)mat * DD * DD + (size_t)(tn + nn) * DD + tk + kq;
    *(ushort4*)(wt_hi + off) = hh;
}

// ---------- fused layer GEMM: h = relu(bn2( relu(bn1(P@W1)) @ W2 )) ----------
// 64 rows x full N=256 per block; t lives in LDS only.
__global__ __launch_bounds__(256, 2) void k_gemm_fused(
    const ushort* __restrict__ A, const ushort* __restrict__ W1t,
    const ushort* __restrict__ W2t,
    const float* __restrict__ b1, const float* __restrict__ g1,
    const float* __restrict__ be1, const float* __restrict__ m1,
    const float* __restrict__ v1,
    const float* __restrict__ b2, const float* __restrict__ g2,
    const float* __restrict__ be2, const float* __restrict__ m2,
    const float* __restrict__ v2,
    ushort* __restrict__ O)
{
    __shared__ alignas(16) ushort As[64][40];    //  5,120 B
    __shared__ alignas(16) ushort Ws[256][40];   // 20,480 B
    __shared__ alignas(16) ushort Ts[64][264];   // 33,792 B  (t tile, 8-pad)

    int tid = threadIdx.x;
    int x  = blockIdx.x & 7;                 // XCD-aligned with spmm partition
    int lm = blockIdx.x >> 3;
    int m0 = x * 8192 + lm * 64;
    int lane = tid & 63;
    int w = tid >> 6;
    int wm = w & 1, wn = w >> 1;             // wave tile: 32m x 128n
    int lr = lane & 15, kg = lane >> 4;
    int rg = lane >> 4;

    f32x4 acc[2][8];
    #pragma unroll
    for (int m = 0; m < 2; ++m)
        #pragma unroll
        for (int n = 0; n < 8; ++n) acc[m][n] = (f32x4)0.f;

    // ---- phase 1: t = relu(bn1(A @ W1)) ----
    for (int kc = 0; kc < 8; ++kc) {
        int k0 = kc * 32;
        __syncthreads();
        {   // A tile: 64 rows x 32 k
            int r = tid >> 2, k8 = (tid & 3) * 8;
            *(float4*)&As[r][k8] = *(const float4*)(A + (size_t)(m0 + r) * DD + k0 + k8);
        }
        #pragma unroll
        for (int i = 0; i < 4; ++i) {        // W1^T tile: 256 n x 32 k
            int idx = tid + i * 256;
            int r = idx >> 2, k8 = (idx & 3) * 8;
            *(float4*)&Ws[r][k8] = *(const float4*)(W1t + (size_t)r * DD + k0 + k8);
        }
        __syncthreads();
        bf16x8 ah[2], bh[8];
        #pragma unroll
        for (int m = 0; m < 2; ++m)
            ah[m] = *(const bf16x8*)&As[wm * 32 + m * 16 + lr][kg * 8];
        #pragma unroll
        for (int n = 0; n < 8; ++n)
            bh[n] = *(const bf16x8*)&Ws[wn * 128 + n * 16 + lr][kg * 8];
        #pragma unroll
        for (int m = 0; m < 2; ++m)
            #pragma unroll
            for (int n = 0; n < 8; ++n)
                acc[m][n] = __builtin_amdgcn_mfma_f32_16x16x32_bf16(ah[m], bh[n], acc[m][n], 0, 0, 0);
    }
    // epilogue 1: bn1+relu -> Ts (bf16)
    {
        float sN[8], svN[8];
        #pragma unroll
        for (int n = 0; n < 8; ++n) {
            int jj = wn * 128 + n * 16 + lr;
            sN[n]  = g1[jj] * rsqrtf(v1[jj] + EPSV);
            svN[n] = (b1[jj] - m1[jj]) * sN[n] + be1[jj];
        }
        #pragma unroll
        for (int m = 0; m < 2; ++m)
            #pragma unroll
            for (int n = 0; n < 8; ++n) {
                int cc = wn * 128 + n * 16 + lr;
                #pragma unroll
                for (int r = 0; r < 4; ++r) {
                    float y = acc[m][n][r] * sN[n] + svN[n];
                    Ts[wm * 32 + m * 16 + rg * 4 + r][cc] = f2bf(y > 0.f ? y : 0.f);
                }
            }
    }
    #pragma unroll
    for (int m = 0; m < 2; ++m)
        #pragma unroll
        for (int n = 0; n < 8; ++n) acc[m][n] = (f32x4)0.f;

    // ---- phase 2: h = relu(bn2(t @ W2)), t read from Ts ----
    for (int kc = 0; kc < 8; ++kc) {
        int k0 = kc * 32;
        __syncthreads();                     // Ts complete / Ws reusable
        #pragma unroll
        for (int i = 0; i < 4; ++i) {        // W2^T tile: 256 n x 32 k
            int idx = tid + i * 256;
            int r = idx >> 2, k8 = (idx & 3) * 8;
            *(float4*)&Ws[r][k8] = *(const float4*)(W2t + (size_t)r * DD + k0 + k8);
        }
        __syncthreads();
        bf16x8 ah[2], bh[8];
        #pragma unroll
        for (int m = 0; m < 2; ++m)
            ah[m] = *(const bf16x8*)&Ts[wm * 32 + m * 16 + lr][k0 + kg * 8];
        #pragma unroll
        for (int n = 0; n < 8; ++n)
            bh[n] = *(const bf16x8*)&Ws[wn * 128 + n * 16 + lr][kg * 8];
        #pragma unroll
        for (int m = 0; m < 2; ++m)
            #pragma unroll
            for (int n = 0; n < 8; ++n)
                acc[m][n] = __builtin_amdgcn_mfma_f32_16x16x32_bf16(ah[m], bh[n], acc[m][n], 0, 0, 0);
    }
    __syncthreads();                         // all Ts reads done before overwrite

    // epilogue 2: bn2+relu -> Ts (reuse as repack scratch) -> coalesced store
    {
        float sN[8], svN[8];
        #pragma unroll
        for (int n = 0; n < 8; ++n) {
            int jj = wn * 128 + n * 16 + lr;
            sN[n]  = g2[jj] * rsqrtf(v2[jj] + EPSV);
            svN[n] = (b2[jj] - m2[jj]) * sN[n] + be2[jj];
        }
        #pragma unroll
        for (int m = 0; m < 2; ++m)
            #pragma unroll
            for (int n = 0; n < 8; ++n) {
                int cc = wn * 128 + n * 16 + lr;
                #pragma unroll
                for (int r = 0; r < 4; ++r) {
                    float y = acc[m][n][r] * sN[n] + svN[n];
                    Ts[wm * 32 + m * 16 + rg * 4 + r][cc] = f2bf(y > 0.f ? y : 0.f);
                }
            }
        // wave-private readback (in-order DS + compiler waitcnt give visibility)
        #pragma unroll
        for (int i = 0; i < 8; ++i) {
            int cid = lane + i * 64;
            int row = cid >> 4, c8 = cid & 15;
            u16x8 vv = *(const u16x8*)&Ts[wm * 32 + row][wn * 128 + c8 * 8];
            *(u16x8*)(O + (size_t)(m0 + wm * 32 + row) * DD + wn * 128 + c8 * 8) = vv;
        }
    }
}

// ---------- layer-0 score: batch-independent; ASSIGNS output ----------
__global__ __launch_bounds__(64) void k_score0(const float4* __restrict__ emo,
                                               const float4* __restrict__ pw,
                                               const float* __restrict__ pb,
                                               float* __restrict__ out)
{
    int q = blockIdx.x, t = threadIdx.x;
    float4 e = emo[q * 64 + t], wv = pw[t];
    float s = e.x * wv.x + e.y * wv.y + e.z * wv.z + e.w * wv.w;
    #pragma unroll
    for (int off = 32; off > 0; off >>= 1) s += __shfl_down(s, off);
    if (t == 0) {
        s += pb[0];
        for (int b = 0; b < BB; ++b) out[b * QQ + q] = s;
    }
}

// ---------- score layers 1..4 ----------
__global__ __launch_bounds__(64) void k_score2(const ushort4* __restrict__ hhi,
                                               const float4* __restrict__ pw,
                                               const float* __restrict__ pb, int l,
                                               float* __restrict__ out)
{
    int bid = blockIdx.x;
    int b = bid / QQ, q = bid % QQ;
    int t = threadIdx.x;
    size_t o = ((size_t)b * NN + q) * 64 + t;
    ushort4 hh = hhi[o];
    float4 wv = pw[l * 64 + t];
    float sum = bf2f(hh.x) * wv.x + bf2f(hh.y) * wv.y +
                bf2f(hh.z) * wv.z + bf2f(hh.w) * wv.w;
    #pragma unroll
    for (int off = 32; off > 0; off >>= 1) sum += __shfl_down(sum, off);
    if (t == 0) out[bid] += sum + pb[l];
}

__global__ void k_sigmoid(float* out)
{
    int i = threadIdx.x + blockIdx.x * blockDim.x;
    if (i < BB * QQ) out[i] = 1.f / (1.f + expf(-out[i]));
}

extern "C" void kernel_launch(void* const* d_in, const int* in_sizes, int n_in,
                              void* d_out, int out_size, void* d_ws, size_t ws_size,
                              hipStream_t stream)
{
    const float* batch = (const float*)d_in[0];
    const int*   edges = (const int*)d_in[1];
    const float* emo   = (const float*)d_in[2];
    const float* w1    = (const float*)d_in[3];
    const float* b1    = (const float*)d_in[4];
    const float* m_g   = (const float*)d_in[5];
    const float* m_b   = (const float*)d_in[6];
    const float* m_m   = (const float*)d_in[7];
    const float* m_v   = (const float*)d_in[8];
    const float* w2    = (const float*)d_in[9];
    const float* b2    = (const float*)d_in[10];
    const float* g_g   = (const float*)d_in[11];
    const float* g_b   = (const float*)d_in[12];
    const float* g_m   = (const float*)d_in[13];
    const float* g_v   = (const float*)d_in[14];
    const float* pw    = (const float*)d_in[15];
    const float* pb    = (const float*)d_in[16];
    float* out = (float*)d_out;

    const size_t HSZ = (size_t)BB * NN * DD;
    const size_t WT  = (size_t)8 * DD * DD;

    ushort* h_hi = (ushort*)d_ws;
    ushort* P_hi = h_hi + HSZ;
    ushort* wt_hi = P_hi + HSZ;
    int* cnt     = (int*)(wt_hi + WT);
    int* row_ptr = cnt + NN;
    int* cursor  = row_ptr + (NN + 4);
    int* col     = cursor + NN;            // 16B-aligned

    const int* src = edges;
    const int* dst = edges + EE;

    hipMemsetAsync(cnt, 0, NN * sizeof(int), stream);
    k_count<<<EE / 256, 256, 0, stream>>>(src, cnt);
    k_scan<<<1, 256, 0, stream>>>(cnt, row_ptr, cursor);
    k_fill<<<EE / 256, 256, 0, stream>>>(src, dst, cursor, col);
    k_wprep<<<512, 256, 0, stream>>>(w1, w2, wt_hi);
    k_prep0<<<4096, 256, 0, stream>>>((const float4*)batch, (const float4*)emo,
                                      (ushort4*)h_hi);
    k_score0<<<QQ, 64, 0, stream>>>((const float4*)emo, (const float4*)pw, pb, out);

    for (int l = 0; l < LL; ++l) {
        k_spmm6<<<8192, 256, 0, stream>>>(h_hi, row_ptr, col, P_hi);
        k_gemm_fused<<<1024, 256, 0, stream>>>(
            P_hi,
            wt_hi + (size_t)l * DD * DD, wt_hi + (size_t)(4 + l) * DD * DD,
            b1 + l * DD, m_g + l * DD, m_b + l * DD, m_m + l * DD, m_v + l * DD,
            b2 + l * DD, g_g + l * DD, g_b + l * DD, g_m + l * DD, g_v + l * DD,
            h_hi);
        k_score2<<<BB * QQ, 64, 0, stream>>>((const ushort4*)h_hi,
                                             (const float4*)pw, pb, l + 1, out);
    }
    k_sigmoid<<<1, 288, 0, stream>>>(out);
}